// Round 7
// baseline (159.505 us; speedup 1.0000x reference)
//
#include <hip/hip_runtime.h>
#include <math.h>

#define D 768
#define NE 8
#define NTOK 6192      // 32*129 + 16*129
#define MEN_TOK0 4128  // 32*129

typedef __attribute__((ext_vector_type(8))) short short8;   // 8 x bf16
typedef __attribute__((ext_vector_type(4))) short short4b;  // 4 x bf16
typedef __attribute__((ext_vector_type(4))) float floatx4;  // MFMA C/D

__device__ __forceinline__ short f2bf(float f) {
  union { float f; unsigned u; } x; x.f = f;
  unsigned r = x.u + 0x7fffu + ((x.u >> 16) & 1u);
  return (short)(r >> 16);
}
__device__ __forceinline__ float bf2f(short s) {
  union { unsigned u; float f; } x; x.u = ((unsigned)(unsigned short)s) << 16;
  return x.f;
}

// async global->LDS 16B: wave-uniform LDS base, per-lane global src (lane*16B dest stride)
__device__ __forceinline__ void gload16(const short* g, short8* lds_base) {
  __builtin_amdgcn_global_load_lds(
      (const __attribute__((address_space(1))) unsigned int*)g,
      (__attribute__((address_space(3))) unsigned int*)lds_base,
      16, 0, 0);
}

// Map concatenated token index -> source row pointer (virtual concat, no copy).
__device__ __forceinline__ const float* token_row(int t,
    const float* __restrict__ ecls, const float* __restrict__ etok,
    const float* __restrict__ mcls, const float* __restrict__ mtok) {
  if (t < MEN_TOK0) {
    int n = t / 129, s = t - n * 129;
    return (s == 0) ? (ecls + n * D) : (etok + (size_t)(n * 128 + s - 1) * D);
  } else {
    int tm = t - MEN_TOK0;
    int b = tm / 129, s = tm - b * 129;
    return (s == 0) ? (mcls + b * D) : (mtok + (size_t)(b * 128 + s - 1) * D);
  }
}

// ---------------- prep: fused gate (blocks 0..1547) + weight transpose/cvt
__global__ __launch_bounds__(256) void prep_kernel(
    const float* __restrict__ ecls, const float* __restrict__ etok,
    const float* __restrict__ mcls, const float* __restrict__ mtok,
    const float* __restrict__ gate_w, const float* __restrict__ gate_b,
    const float* __restrict__ exp_w, const float* __restrict__ wq,
    const float* __restrict__ wk, const float* __restrict__ wv,
    int* __restrict__ te1, int* __restrict__ te2,
    float* __restrict__ tw1, float* __restrict__ tw2,
    short* __restrict__ Xb, short* __restrict__ expwT, short* __restrict__ wT) {
  __shared__ float tbuf[64][65];
  int bid = blockIdx.x;
  int tid = threadIdx.x;
  if (bid < 1548) {
    // ---- gate part
    int t = bid * 4 + (tid >> 6);
    int lane = tid & 63;
    const float* xr = token_row(t, ecls, etok, mcls, mtok);
    float acc[NE];
#pragma unroll
    for (int e = 0; e < NE; ++e) acc[e] = 0.f;
#pragma unroll
    for (int it = 0; it < 3; ++it) {
      int d0 = lane * 4 + it * 256;
      floatx4 x = *(const floatx4*)(xr + d0);
      short4b xb;
#pragma unroll
      for (int q = 0; q < 4; ++q) {
        xb[q] = f2bf(x[q]);
        float xv = x[q];
#pragma unroll
        for (int e = 0; e < NE; ++e) acc[e] += xv * gate_w[(d0 + q) * NE + e];
      }
      *(short4b*)(Xb + (size_t)t * D + d0) = xb;
    }
#pragma unroll
    for (int e = 0; e < NE; ++e) {
#pragma unroll
      for (int off = 32; off > 0; off >>= 1) acc[e] += __shfl_down(acc[e], off);
    }
    if (lane == 0) {
      float lg[NE];
#pragma unroll
      for (int e = 0; e < NE; ++e) lg[e] = acc[e] + gate_b[e];
      int e1 = 0;
#pragma unroll
      for (int e = 1; e < NE; ++e) if (lg[e] > lg[e1]) e1 = e;
      int e2 = (e1 == 0) ? 1 : 0;
#pragma unroll
      for (int e = 0; e < NE; ++e) {
        if (e != e1 && lg[e] > lg[e2]) e2 = e;
      }
      float w1 = 1.f / (1.f + __expf(lg[e2] - lg[e1]));
      te1[t] = e1; te2[t] = e2;
      tw1[t] = w1; tw2[t] = 1.f - w1;
    }
  } else {
    // ---- tcvt part
    int zz = bid - 1548;
    int z = zz / 144, rem = zz % 144;
    int k0 = (rem / 12) * 64, o0 = (rem % 12) * 64;
    const float* src; short* dst;
    if (z < 8) { src = exp_w + (size_t)z * D * D; dst = expwT + (size_t)z * D * D; }
    else { src = (z == 8) ? wq : (z == 9) ? wk : wv; dst = wT + (size_t)(z - 8) * D * D; }
    int tx = tid & 63, ty = tid >> 6;
#pragma unroll
    for (int i = 0; i < 16; ++i) {
      int k = i * 4 + ty;
      tbuf[k][tx] = src[(size_t)(k0 + k) * D + o0 + tx];
    }
    __syncthreads();
#pragma unroll
    for (int i = 0; i < 16; ++i) {
      int o = i * 4 + ty;
      dst[(size_t)(o0 + o) * D + k0 + tx] = f2bf(tbuf[tx][o]);
    }
  }
}

// ---------------- route: fused histogram + compaction (single block, LDS atomics)
__global__ __launch_bounds__(1024) void route_kernel(
    const int* __restrict__ te1, const int* __restrict__ te2,
    int* __restrict__ lst_tok, int* __restrict__ slot1, int* __restrict__ slot2,
    int* __restrict__ cnt, int* __restrict__ basee) {
  __shared__ int hist[NE];
  __shared__ int base_s[NE];
  int tid = threadIdx.x;
  if (tid < NE) hist[tid] = 0;
  __syncthreads();
  for (int t = tid; t < NTOK; t += 1024) {
    atomicAdd(&hist[te1[t]], 1);
    atomicAdd(&hist[te2[t]], 1);
  }
  __syncthreads();
  if (tid == 0) {
    int acc = 0;
    for (int e = 0; e < NE; ++e) {
      base_s[e] = acc;
      cnt[e] = hist[e];
      basee[e] = acc;
      acc += hist[e];
    }
  }
  __syncthreads();
  if (tid < NE) hist[tid] = 0;   // reuse as running rank counters
  __syncthreads();
  for (int t = tid; t < NTOK; t += 1024) {
    int e1 = te1[t], e2 = te2[t];
    int r1 = atomicAdd(&hist[e1], 1);
    int r2 = atomicAdd(&hist[e2], 1);
    int s1 = base_s[e1] + r1;
    int s2 = base_s[e2] + r2;
    slot1[t] = s1; slot2[t] = s2;
    lst_tok[s1] = t; lst_tok[s2] = t;
  }
}

// ---------------- grouped expert GEMM (MFMA bf16), 128x128 tile, 2x2 waves
// staging via global_load_lds: linear LDS dest + inverse-swizzled global src
// flattened grid: e = id&7 (XCD pinning), r = id>>3: ob = r%6, tb = r/6
__global__ __launch_bounds__(256) void moe_kernel(
    const short* __restrict__ Xb, const short* __restrict__ expwT,
    const int* __restrict__ cnt, const int* __restrict__ basee,
    const int* __restrict__ lst_tok, short* __restrict__ EO) {
  int id = blockIdx.x;
  int e = id & 7;
  int r = id >> 3;
  int ob = r % 6;
  int tb = r / 6;           // 0..48
  int count = cnt[e];
  int t0 = tb * 128;
  if (t0 >= count) return;
  int o0 = ob * 128;
  int gb = basee[e];

  __shared__ short8 As[1024];   // 128 rows x 8 chunks; slot (row<<3)+cc holds data[row][cc^(row&7)]
  __shared__ short8 Bs[1024];
  __shared__ int stok[128];

  int tid = threadIdx.x;
  int l = tid & 63, w = tid >> 6;
  int wr = w >> 1, wc = w & 1;

  if (tid < 128) {
    int p = t0 + tid;
    stok[tid] = lst_tok[gb + (p < count ? p : 0)];
  }
  __syncthreads();

  const short* Bg = expwT + (size_t)e * D * D;
  // hoist per-lane source pointers (k0-invariant): slot s -> row=s>>3, cc=s&7, src chunk cc^(row&7)
  const short* srcA[4];
  const short* srcB[4];
#pragma unroll
  for (int q = 0; q < 4; ++q) {
    int s = (q << 8) + (w << 6) + l;
    int row = s >> 3, cc = s & 7;
    int csrc = (cc ^ (row & 7)) * 8;
    srcA[q] = Xb + (size_t)stok[row] * D + csrc;
    srcB[q] = Bg + (size_t)(o0 + row) * D + csrc;
  }

  floatx4 acc[4][4];
#pragma unroll
  for (int ai = 0; ai < 4; ++ai)
#pragma unroll
    for (int bj = 0; bj < 4; ++bj) acc[ai][bj] = (floatx4){0.f, 0.f, 0.f, 0.f};

  for (int k0 = 0; k0 < D; k0 += 64) {
    __syncthreads();
#pragma unroll
    for (int q = 0; q < 4; ++q) {
      gload16(srcA[q] + k0, &As[(q << 8) + (w << 6)]);
      gload16(srcB[q] + k0, &Bs[(q << 8) + (w << 6)]);
    }
    __syncthreads();
#pragma unroll
    for (int kk = 0; kk < 2; ++kk) {
      int kc = kk * 4 + (l >> 4);
      short8 a[4], bb[4];
#pragma unroll
      for (int ai = 0; ai < 4; ++ai) {
        int ar = wr * 64 + ai * 16 + (l & 15);
        a[ai] = As[(ar << 3) + (kc ^ (ar & 7))];
      }
#pragma unroll
      for (int bj = 0; bj < 4; ++bj) {
        int br = wc * 64 + bj * 16 + (l & 15);
        bb[bj] = Bs[(br << 3) + (kc ^ (br & 7))];
      }
#pragma unroll
      for (int ai = 0; ai < 4; ++ai)
#pragma unroll
        for (int bj = 0; bj < 4; ++bj)
          acc[ai][bj] = __builtin_amdgcn_mfma_f32_16x16x32_bf16(a[ai], bb[bj], acc[ai][bj], 0, 0, 0);
    }
  }

  // epilogue: C/D layout col=lane&15, row=(lane>>4)*4+reg
#pragma unroll
  for (int ai = 0; ai < 4; ++ai) {
#pragma unroll
    for (int rr = 0; rr < 4; ++rr) {
      int rowl = wr * 64 + ai * 16 + ((l >> 4) << 2) + rr;
      int p = t0 + rowl;
      if (p < count) {
        size_t off = (size_t)(gb + p) * D;
#pragma unroll
        for (int bj = 0; bj < 4; ++bj) {
          int col = o0 + wc * 64 + bj * 16 + (l & 15);
          EO[off + col] = f2bf(acc[ai][bj][rr]);
        }
      }
    }
  }
}

// ---------------- QKV projections (MFMA bf16) with FUSED MoE-combine A-staging
// B via global_load_lds; A manual (needs combine arithmetic)
__global__ __launch_bounds__(256) void qkv_kernel(
    const short* __restrict__ EO,
    const int* __restrict__ te1, const int* __restrict__ te2,
    const float* __restrict__ tw1, const float* __restrict__ tw2,
    const int* __restrict__ slot1, const int* __restrict__ slot2,
    const float* __restrict__ exp_b, const short* __restrict__ wT,
    const float* __restrict__ bq, const float* __restrict__ bk,
    const float* __restrict__ bv,
    short* __restrict__ Qb, short* __restrict__ Kb, short* __restrict__ Vb) {
  int id = blockIdx.x;
  int z, r;
  if (id < 384)      { z = 0; r = id; }
  else if (id < 576) { z = 1; r = id - 384; }
  else               { z = 2; r = id - 576; }
  int tb = r / 6, ob = r % 6;
  int o0 = ob * 128;
  int base = (z == 0) ? 0 : MEN_TOK0;
  const short* W = wT + (size_t)z * D * D;
  const float* bias = (z == 0) ? bq : (z == 1) ? bk : bv;
  int tokbase = base + (tb >> 1) * 129 + 1 + (tb & 1) * 64;

  __shared__ short8 As[512];    // 64 rows x 8 chunks
  __shared__ short8 Bs[1024];   // 128 rows x 8 chunks
  __shared__ int   ss1[64], ss2[64];
  __shared__ float sw1[64], sw2[64];
  __shared__ int   se1[64], se2[64];

  int tid = threadIdx.x;
  int l = tid & 63, w = tid >> 6;
  int wr = w >> 1, wc = w & 1;

  if (tid < 64) {
    int t = tokbase + tid;
    ss1[tid] = slot1[t]; ss2[tid] = slot2[t];
    sw1[tid] = tw1[t];   sw2[tid] = tw2[t];
    se1[tid] = te1[t] * D; se2[tid] = te2[t] * D;
  }

  const short* srcB[4];
#pragma unroll
  for (int q = 0; q < 4; ++q) {
    int s = (q << 8) + (w << 6) + l;
    int row = s >> 3, cc = s & 7;
    int csrc = (cc ^ (row & 7)) * 8;
    srcB[q] = W + (size_t)(o0 + row) * D + csrc;
  }

  floatx4 acc[2][4];
#pragma unroll
  for (int ai = 0; ai < 2; ++ai)
#pragma unroll
    for (int bj = 0; bj < 4; ++bj) acc[ai][bj] = (floatx4){0.f, 0.f, 0.f, 0.f};

  for (int k0 = 0; k0 < D; k0 += 64) {
    __syncthreads();
#pragma unroll
    for (int q = 0; q < 4; ++q)
      gload16(srcB[q] + k0, &Bs[(q << 8) + (w << 6)]);
#pragma unroll
    for (int q = 0; q < 2; ++q) {
      int p = q * 256 + tid;
      int row = p >> 3, c = p & 7;
      int off = k0 + c * 8;
      short8 a1 = *(const short8*)(EO + (size_t)ss1[row] * D + off);
      short8 a2 = *(const short8*)(EO + (size_t)ss2[row] * D + off);
      const float* bp1 = exp_b + se1[row] + off;
      const float* bp2 = exp_b + se2[row] + off;
      float w1 = sw1[row], w2 = sw2[row];
      short8 v;
#pragma unroll
      for (int j = 0; j < 8; ++j)
        v[j] = f2bf(w1 * (bf2f(a1[j]) + bp1[j]) + w2 * (bf2f(a2[j]) + bp2[j]));
      As[(row << 3) + (c ^ (row & 7))] = v;
    }
    __syncthreads();
#pragma unroll
    for (int kk = 0; kk < 2; ++kk) {
      int kc = kk * 4 + (l >> 4);
      short8 a[2], bb[4];
#pragma unroll
      for (int ai = 0; ai < 2; ++ai) {
        int ar = wr * 32 + ai * 16 + (l & 15);
        a[ai] = As[(ar << 3) + (kc ^ (ar & 7))];
      }
#pragma unroll
      for (int bj = 0; bj < 4; ++bj) {
        int br = wc * 64 + bj * 16 + (l & 15);
        bb[bj] = Bs[(br << 3) + (kc ^ (br & 7))];
      }
#pragma unroll
      for (int ai = 0; ai < 2; ++ai)
#pragma unroll
        for (int bj = 0; bj < 4; ++bj)
          acc[ai][bj] = __builtin_amdgcn_mfma_f32_16x16x32_bf16(a[ai], bb[bj], acc[ai][bj], 0, 0, 0);
    }
  }

#pragma unroll
  for (int ai = 0; ai < 2; ++ai) {
#pragma unroll
    for (int rr = 0; rr < 4; ++rr) {
      int rowl = wr * 32 + ai * 16 + ((l >> 4) << 2) + rr;
      size_t rglob = (size_t)tb * 64 + rowl;
#pragma unroll
      for (int bj = 0; bj < 4; ++bj) {
        int col = o0 + wc * 64 + bj * 16 + (l & 15);
        float v = acc[ai][bj][rr] + bias[col];
        if (z == 0)      Qb[rglob * D + col] = f2bf(v);
        else if (z == 1) Kb[rglob * D + col] = f2bf(v);
        else             Vb[rglob * D + col] = f2bf(v);
      }
    }
  }
}

// ---------------- fused scores GEMM (MFMA) + in-register softmax + column-mean
// Q/K staging via global_load_lds. flattened grid: id = b*32 + n
__global__ __launch_bounds__(256) void attn_kernel(
    const short* __restrict__ Qb, const short* __restrict__ Kb,
    float* __restrict__ pbar_ws) {
  int id = blockIdx.x;
  int n = id & 31, b = id >> 5;
  __shared__ short8 Qs[1024];
  __shared__ short8 Ks[1024];
  __shared__ float pb[128];
  int tid = threadIdx.x;
  int l = tid & 63, w = tid >> 6;
  if (tid < 128) pb[tid] = 0.f;

  floatx4 acc[2][8];
#pragma unroll
  for (int i = 0; i < 2; ++i)
#pragma unroll
    for (int j = 0; j < 8; ++j) acc[i][j] = (floatx4){0.f, 0.f, 0.f, 0.f};

  const short* qg = Qb + (size_t)n * 128 * D;
  const short* kg = Kb + (size_t)b * 128 * D;

  const short* srcQ[4];
  const short* srcK[4];
#pragma unroll
  for (int q = 0; q < 4; ++q) {
    int s = (q << 8) + (w << 6) + l;
    int row = s >> 3, cc = s & 7;
    int csrc = (cc ^ (row & 7)) * 8;
    srcQ[q] = qg + (size_t)row * D + csrc;
    srcK[q] = kg + (size_t)row * D + csrc;
  }

  for (int k0 = 0; k0 < D; k0 += 64) {
    __syncthreads();
#pragma unroll
    for (int q = 0; q < 4; ++q) {
      gload16(srcQ[q] + k0, &Qs[(q << 8) + (w << 6)]);
      gload16(srcK[q] + k0, &Ks[(q << 8) + (w << 6)]);
    }
    __syncthreads();
#pragma unroll
    for (int kk = 0; kk < 2; ++kk) {
      int kc = kk * 4 + (l >> 4);
      short8 a[2], bb[8];
#pragma unroll
      for (int i = 0; i < 2; ++i) {
        int ar = w * 32 + i * 16 + (l & 15);
        a[i] = Qs[(ar << 3) + (kc ^ (ar & 7))];
      }
#pragma unroll
      for (int j = 0; j < 8; ++j) {
        int br = j * 16 + (l & 15);
        bb[j] = Ks[(br << 3) + (kc ^ (br & 7))];
      }
#pragma unroll
      for (int i = 0; i < 2; ++i)
#pragma unroll
        for (int j = 0; j < 8; ++j)
          acc[i][j] = __builtin_amdgcn_mfma_f32_16x16x32_bf16(a[i], bb[j], acc[i][j], 0, 0, 0);
    }
  }

  const float scale = 0.03608439182435161f; // 1/sqrt(768)
  float colsum[8];
#pragma unroll
  for (int j = 0; j < 8; ++j) colsum[j] = 0.f;

#pragma unroll
  for (int i = 0; i < 2; ++i) {
#pragma unroll
    for (int r = 0; r < 4; ++r) {
      float mx = -3.0e38f;
#pragma unroll
      for (int j = 0; j < 8; ++j) mx = fmaxf(mx, acc[i][j][r]);
      mx = fmaxf(mx, __shfl_xor(mx, 1));
      mx = fmaxf(mx, __shfl_xor(mx, 2));
      mx = fmaxf(mx, __shfl_xor(mx, 4));
      mx = fmaxf(mx, __shfl_xor(mx, 8));
      float pv[8], sm = 0.f;
#pragma unroll
      for (int j = 0; j < 8; ++j) { pv[j] = __expf((acc[i][j][r] - mx) * scale); sm += pv[j]; }
      sm += __shfl_xor(sm, 1);
      sm += __shfl_xor(sm, 2);
      sm += __shfl_xor(sm, 4);
      sm += __shfl_xor(sm, 8);
      float inv = 1.f / sm;
#pragma unroll
      for (int j = 0; j < 8; ++j) colsum[j] += pv[j] * inv;
    }
  }
#pragma unroll
  for (int j = 0; j < 8; ++j) {
    colsum[j] += __shfl_xor(colsum[j], 16);
    colsum[j] += __shfl_xor(colsum[j], 32);
  }
  if (l < 16) {
#pragma unroll
    for (int j = 0; j < 8; ++j) atomicAdd(&pb[j * 16 + l], colsum[j]);
  }
  __syncthreads();
  if (tid < 128) pbar_ws[((size_t)n * 16 + b) * 128 + tid] = pb[tid] * (1.f / 128.f);
}

// ---------------- ctx[b,n,d] = sum_m pbar[n,b,m] * V[b,m,d]  (V read once, bf16)
__global__ __launch_bounds__(256) void pv_kernel(
    const float* __restrict__ pbar_ws, const short* __restrict__ Vb,
    float* __restrict__ CTX) {
  int b = blockIdx.x, dc = blockIdx.y;
  __shared__ float pbs[4096];   // [n][m]
  int tid = threadIdx.x;
#pragma unroll
  for (int i = 0; i < 16; ++i) {
    int idx = i * 256 + tid;
    int nn = idx >> 7, m = idx & 127;
    pbs[idx] = pbar_ws[((size_t)nn * 16 + b) * 128 + m];
  }
  __syncthreads();
  int d = dc * 256 + tid;
  float acc[32];
#pragma unroll
  for (int nn = 0; nn < 32; ++nn) acc[nn] = 0.f;
  const short* vb = Vb + (size_t)b * 128 * D + d;
  for (int m = 0; m < 128; ++m) {
    float v = bf2f(vb[(size_t)m * D]);
#pragma unroll
    for (int nn = 0; nn < 32; ++nn) acc[nn] += pbs[nn * 128 + m] * v;
  }
#pragma unroll
  for (int nn = 0; nn < 32; ++nn) CTX[((size_t)b * 32 + nn) * D + d] = acc[nn];
}

__device__ __forceinline__ float blockSum(float v, volatile float* red, int tid) {
#pragma unroll
  for (int off = 32; off > 0; off >>= 1) v += __shfl_down(v, off);
  __syncthreads();
  if ((tid & 63) == 0) red[tid >> 6] = v;
  __syncthreads();
  return red[0] + red[1] + red[2] + red[3];
}

// ---------------- LayerNorm + final dots (ent-cls MoE row computed inline, fp32)
__global__ __launch_bounds__(256) void ln_dot_kernel(
    const float* __restrict__ CTX, const short* __restrict__ EO,
    const int* __restrict__ te1, const int* __restrict__ te2,
    const float* __restrict__ tw1, const float* __restrict__ tw2,
    const int* __restrict__ slot1, const int* __restrict__ slot2,
    const float* __restrict__ exp_b,
    const float* __restrict__ ecls, const float* __restrict__ mcls,
    const float* __restrict__ ln_w, const float* __restrict__ ln_b,
    float* __restrict__ out) {
  __shared__ float red[4];
  int bn = blockIdx.x;
  int b = bn >> 5, n = bn & 31;
  int tid = threadIdx.x;
  const float* cr = CTX + (size_t)bn * D;
  float ctx[3];
#pragma unroll
  for (int r = 0; r < 3; ++r) ctx[r] = cr[tid + r * 256];
  float mu = blockSum(ctx[0] + ctx[1] + ctx[2], red, tid) * (1.f / 768.f);
  float vs = 0.f;
#pragma unroll
  for (int r = 0; r < 3; ++r) { float c = ctx[r] - mu; vs += c * c; }
  float var = blockSum(vs, red, tid) * (1.f / 768.f);
  float rstd = rsqrtf(var + 1e-5f);

  int t = n * 129;   // entity cls token
  int e1 = te1[t], e2 = te2[t];
  float w1 = tw1[t], w2 = tw2[t];
  const short* eo1 = EO + (size_t)slot1[t] * D;
  const short* eo2 = EO + (size_t)slot2[t] * D;
  const float* bb1 = exp_b + e1 * D;
  const float* bb2 = exp_b + e2 * D;

  float g2l_p = 0.f, g2g_p = 0.f;
#pragma unroll
  for (int r = 0; r < 3; ++r) {
    int d = tid + r * 256;
    float cl = (ctx[r] - mu) * rstd * ln_w[d] + ln_b[d];
    float em = w1 * (bf2f(eo1[d]) + bb1[d]) + w2 * (bf2f(eo2[d]) + bb2[d]);
    g2l_p += em * cl;
    g2g_p += mcls[(size_t)b * D + d] * ecls[(size_t)n * D + d];
  }
  float g2l = blockSum(g2l_p, red, tid);
  float g2g = blockSum(g2g_p, red, tid);
  if (tid == 0) out[bn] = 0.5f * (g2l + g2g);
}

extern "C" void kernel_launch(void* const* d_in, const int* in_sizes, int n_in,
                              void* d_out, int out_size, void* d_ws, size_t ws_size,
                              hipStream_t stream) {
  const float* ecls   = (const float*)d_in[0];
  const float* etok   = (const float*)d_in[1];
  const float* mcls   = (const float*)d_in[2];
  const float* mtok   = (const float*)d_in[3];
  const float* gate_w = (const float*)d_in[4];
  const float* gate_b = (const float*)d_in[5];
  const float* exp_w  = (const float*)d_in[6];
  const float* exp_b  = (const float*)d_in[7];
  const float* wq     = (const float*)d_in[8];
  const float* bq     = (const float*)d_in[9];
  const float* wk     = (const float*)d_in[10];
  const float* bk     = (const float*)d_in[11];
  const float* wv     = (const float*)d_in[12];
  const float* bv     = (const float*)d_in[13];
  const float* ln_w   = (const float*)d_in[14];
  const float* ln_b   = (const float*)d_in[15];
  float* outp = (float*)d_out;

  char* ws = (char*)d_ws;
  short* Qb    = (short*)(ws + 0);              //  6,291,456 B
  short* Kb    = (short*)(ws + 6291456);        //  3,145,728 B
  short* Vb    = (short*)(ws + 9437184);        //  3,145,728 B (ends 12,582,912)
  short* Xb    = (short*)(ws + 12582912);       //  9,510,912 B (ends 22,093,824)
  short* EO    = (short*)(ws + 22093824);       // 19,021,824 B (ends 41,115,648)
  short* expwT = (short*)(ws + 41115648);       //  9,437,184 B (ends 50,552,832)
  short* wT    = (short*)(ws + 50552832);       //  3,538,944 B (ends 54,091,776)
  float* PBAR  = (float*)(ws + 54091776);       //    262,144 B (ends 54,353,920)
  float* CTX   = (float*)(ws + 54353920);       //  1,572,864 B (ends 55,926,784)
  int*   te1   = (int*)  (ws + 55926784);       //     24,768 B each
  int*   te2   = (int*)  (ws + 55951552);
  float* tw1   = (float*)(ws + 55976320);
  float* tw2   = (float*)(ws + 56001088);
  int*   slot1 = (int*)  (ws + 56025856);
  int*   slot2 = (int*)  (ws + 56050624);
  int*   lst_tok = (int*)(ws + 56075392);       //     49,536 B
  int*   cnt   = (int*)  (ws + 56124928);       //         32 B
  int*   basee = (int*)  (ws + 56124960);       //         32 B  (total 56,124,992)

  prep_kernel<<<1548 + 1584, 256, 0, stream>>>(ecls, etok, mcls, mtok, gate_w, gate_b,
                                               exp_w, wq, wk, wv,
                                               te1, te2, tw1, tw2, Xb, expwT, wT);
  route_kernel<<<1, 1024, 0, stream>>>(te1, te2, lst_tok, slot1, slot2, cnt, basee);
  moe_kernel<<<49 * 6 * 8, 256, 0, stream>>>(Xb, expwT, cnt, basee, lst_tok, EO);
  qkv_kernel<<<768, 256, 0, stream>>>(EO, te1, te2, tw1, tw2, slot1, slot2, exp_b,
                                      wT, bq, bk, bv, Qb, Kb, Vb);
  attn_kernel<<<512, 256, 0, stream>>>(Qb, Kb, PBAR);
  pv_kernel<<<dim3(16, 3), 256, 0, stream>>>(PBAR, Vb, CTX);
  ln_dot_kernel<<<512, 256, 0, stream>>>(CTX, EO, te1, te2, tw1, tw2, slot1, slot2,
                                         exp_b, ecls, mcls, ln_w, ln_b, outp);
}

// Round 8
// 134.132 us; speedup vs baseline: 1.1892x; 1.1892x over previous
//
#include <hip/hip_runtime.h>
#include <math.h>

#define D 768
#define NE 8
#define NTOK 6192      // 32*129 + 16*129
#define MEN_TOK0 4128  // 32*129

typedef __attribute__((ext_vector_type(8))) short short8;   // 8 x bf16
typedef __attribute__((ext_vector_type(4))) short short4b;  // 4 x bf16
typedef __attribute__((ext_vector_type(4))) float floatx4;  // MFMA C/D

__device__ __forceinline__ short f2bf(float f) {
  union { float f; unsigned u; } x; x.f = f;
  unsigned r = x.u + 0x7fffu + ((x.u >> 16) & 1u);
  return (short)(r >> 16);
}
__device__ __forceinline__ float bf2f(short s) {
  union { unsigned u; float f; } x; x.u = ((unsigned)(unsigned short)s) << 16;
  return x.f;
}

// async global->LDS 16B: wave-uniform LDS base, per-lane global src
__device__ __forceinline__ void gload16(const short* g, short8* lds_base) {
  __builtin_amdgcn_global_load_lds(
      (const __attribute__((address_space(1))) unsigned int*)g,
      (__attribute__((address_space(3))) unsigned int*)lds_base,
      16, 0, 0);
}

// Map concatenated token index -> source row pointer (virtual concat, no copy).
__device__ __forceinline__ const float* token_row(int t,
    const float* __restrict__ ecls, const float* __restrict__ etok,
    const float* __restrict__ mcls, const float* __restrict__ mtok) {
  if (t < MEN_TOK0) {
    int n = t / 129, s = t - n * 129;
    return (s == 0) ? (ecls + n * D) : (etok + (size_t)(n * 128 + s - 1) * D);
  } else {
    int tm = t - MEN_TOK0;
    int b = tm / 129, s = tm - b * 129;
    return (s == 0) ? (mcls + b * D) : (mtok + (size_t)(b * 128 + s - 1) * D);
  }
}

// ---------------- prep: fused gate (blocks 0..1547) + weight transpose/cvt
__global__ __launch_bounds__(256) void prep_kernel(
    const float* __restrict__ ecls, const float* __restrict__ etok,
    const float* __restrict__ mcls, const float* __restrict__ mtok,
    const float* __restrict__ gate_w, const float* __restrict__ gate_b,
    const float* __restrict__ exp_w, const float* __restrict__ wq,
    const float* __restrict__ wk, const float* __restrict__ wv,
    int* __restrict__ te1, int* __restrict__ te2,
    float* __restrict__ tw1, float* __restrict__ tw2,
    short* __restrict__ Xb, short* __restrict__ expwT, short* __restrict__ wT) {
  __shared__ float tbuf[64][65];
  int bid = blockIdx.x;
  int tid = threadIdx.x;
  if (bid < 1548) {
    int t = bid * 4 + (tid >> 6);
    int lane = tid & 63;
    const float* xr = token_row(t, ecls, etok, mcls, mtok);
    float acc[NE];
#pragma unroll
    for (int e = 0; e < NE; ++e) acc[e] = 0.f;
#pragma unroll
    for (int it = 0; it < 3; ++it) {
      int d0 = lane * 4 + it * 256;
      floatx4 x = *(const floatx4*)(xr + d0);
      short4b xb;
#pragma unroll
      for (int q = 0; q < 4; ++q) {
        xb[q] = f2bf(x[q]);
        float xv = x[q];
#pragma unroll
        for (int e = 0; e < NE; ++e) acc[e] += xv * gate_w[(d0 + q) * NE + e];
      }
      *(short4b*)(Xb + (size_t)t * D + d0) = xb;
    }
#pragma unroll
    for (int e = 0; e < NE; ++e) {
#pragma unroll
      for (int off = 32; off > 0; off >>= 1) acc[e] += __shfl_down(acc[e], off);
    }
    if (lane == 0) {
      float lg[NE];
#pragma unroll
      for (int e = 0; e < NE; ++e) lg[e] = acc[e] + gate_b[e];
      int e1 = 0;
#pragma unroll
      for (int e = 1; e < NE; ++e) if (lg[e] > lg[e1]) e1 = e;
      int e2 = (e1 == 0) ? 1 : 0;
#pragma unroll
      for (int e = 0; e < NE; ++e) {
        if (e != e1 && lg[e] > lg[e2]) e2 = e;
      }
      float w1 = 1.f / (1.f + __expf(lg[e2] - lg[e1]));
      te1[t] = e1; te2[t] = e2;
      tw1[t] = w1; tw2[t] = 1.f - w1;
    }
  } else {
    int zz = bid - 1548;
    int z = zz / 144, rem = zz % 144;
    int k0 = (rem / 12) * 64, o0 = (rem % 12) * 64;
    const float* src; short* dst;
    if (z < 8) { src = exp_w + (size_t)z * D * D; dst = expwT + (size_t)z * D * D; }
    else { src = (z == 8) ? wq : (z == 9) ? wk : wv; dst = wT + (size_t)(z - 8) * D * D; }
    int tx = tid & 63, ty = tid >> 6;
#pragma unroll
    for (int i = 0; i < 16; ++i) {
      int k = i * 4 + ty;
      tbuf[k][tx] = src[(size_t)(k0 + k) * D + o0 + tx];
    }
    __syncthreads();
#pragma unroll
    for (int i = 0; i < 16; ++i) {
      int o = i * 4 + ty;
      dst[(size_t)(o0 + o) * D + k0 + tx] = f2bf(tbuf[tx][o]);
    }
  }
}

// ---------------- route: fused histogram + compaction (single block, LDS atomics)
__global__ __launch_bounds__(1024) void route_kernel(
    const int* __restrict__ te1, const int* __restrict__ te2,
    int* __restrict__ lst_tok, int* __restrict__ slot1, int* __restrict__ slot2,
    int* __restrict__ cnt, int* __restrict__ basee) {
  __shared__ int hist[NE];
  __shared__ int base_s[NE];
  int tid = threadIdx.x;
  if (tid < NE) hist[tid] = 0;
  __syncthreads();
  for (int t = tid; t < NTOK; t += 1024) {
    atomicAdd(&hist[te1[t]], 1);
    atomicAdd(&hist[te2[t]], 1);
  }
  __syncthreads();
  if (tid == 0) {
    int acc = 0;
    for (int e = 0; e < NE; ++e) {
      base_s[e] = acc;
      cnt[e] = hist[e];
      basee[e] = acc;
      acc += hist[e];
    }
  }
  __syncthreads();
  if (tid < NE) hist[tid] = 0;
  __syncthreads();
  for (int t = tid; t < NTOK; t += 1024) {
    int e1 = te1[t], e2 = te2[t];
    int r1 = atomicAdd(&hist[e1], 1);
    int r2 = atomicAdd(&hist[e2], 1);
    int s1 = base_s[e1] + r1;
    int s2 = base_s[e2] + r2;
    slot1[t] = s1; slot2[t] = s2;
    lst_tok[s1] = t; lst_tok[s2] = t;
  }
}

// ---------------- grouped expert GEMM (MFMA bf16), 128x128 tile, 2x2 waves
// 2-phase double-buffered global_load_lds staging
__global__ __launch_bounds__(256) void moe_kernel(
    const short* __restrict__ Xb, const short* __restrict__ expwT,
    const int* __restrict__ cnt, const int* __restrict__ basee,
    const int* __restrict__ lst_tok, short* __restrict__ EO) {
  int id = blockIdx.x;
  int e = id & 7;
  int r = id >> 3;
  int ob = r % 6;
  int tb = r / 6;
  int count = cnt[e];
  int t0 = tb * 128;
  if (t0 >= count) return;
  int o0 = ob * 128;
  int gb = basee[e];

  __shared__ short8 As[2048];   // 2 bufs x 1024; slot (row<<3)+cc holds data[row][cc^(row&7)]
  __shared__ short8 Bs[2048];
  __shared__ int stok[128];

  int tid = threadIdx.x;
  int l = tid & 63, w = tid >> 6;
  int wr = w >> 1, wc = w & 1;

  if (tid < 128) {
    int p = t0 + tid;
    stok[tid] = lst_tok[gb + (p < count ? p : 0)];
  }
  __syncthreads();

  const short* Bg = expwT + (size_t)e * D * D;
  const short* srcA[4];
  const short* srcB[4];
#pragma unroll
  for (int q = 0; q < 4; ++q) {
    int s = (q << 8) + (w << 6) + l;
    int row = s >> 3, cc = s & 7;
    int csrc = (cc ^ (row & 7)) * 8;
    srcA[q] = Xb + (size_t)stok[row] * D + csrc;
    srcB[q] = Bg + (size_t)(o0 + row) * D + csrc;
  }

  floatx4 acc[4][4];
#pragma unroll
  for (int ai = 0; ai < 4; ++ai)
#pragma unroll
    for (int bj = 0; bj < 4; ++bj) acc[ai][bj] = (floatx4){0.f, 0.f, 0.f, 0.f};

  // prologue: stage k-tile 0 into buffer 0
#pragma unroll
  for (int q = 0; q < 4; ++q) {
    gload16(srcA[q], &As[(q << 8) + (w << 6)]);
    gload16(srcB[q], &Bs[(q << 8) + (w << 6)]);
  }
  __syncthreads();

  for (int it = 0; it < 12; ++it) {
    int cur = (it & 1) << 10;
    if (it < 11) {
      int nxt = cur ^ 1024;
      int k0n = (it + 1) * 64;
#pragma unroll
      for (int q = 0; q < 4; ++q) {
        gload16(srcA[q] + k0n, &As[nxt + (q << 8) + (w << 6)]);
        gload16(srcB[q] + k0n, &Bs[nxt + (q << 8) + (w << 6)]);
      }
    }
#pragma unroll
    for (int kk = 0; kk < 2; ++kk) {
      int kc = kk * 4 + (l >> 4);
      short8 a[4], bb[4];
#pragma unroll
      for (int ai = 0; ai < 4; ++ai) {
        int ar = wr * 64 + ai * 16 + (l & 15);
        a[ai] = As[cur + (ar << 3) + (kc ^ (ar & 7))];
      }
#pragma unroll
      for (int bj = 0; bj < 4; ++bj) {
        int br = wc * 64 + bj * 16 + (l & 15);
        bb[bj] = Bs[cur + (br << 3) + (kc ^ (br & 7))];
      }
#pragma unroll
      for (int ai = 0; ai < 4; ++ai)
#pragma unroll
        for (int bj = 0; bj < 4; ++bj)
          acc[ai][bj] = __builtin_amdgcn_mfma_f32_16x16x32_bf16(a[ai], bb[bj], acc[ai][bj], 0, 0, 0);
    }
    __syncthreads();
  }

  // epilogue: C/D layout col=lane&15, row=(lane>>4)*4+reg
#pragma unroll
  for (int ai = 0; ai < 4; ++ai) {
#pragma unroll
    for (int rr = 0; rr < 4; ++rr) {
      int rowl = wr * 64 + ai * 16 + ((l >> 4) << 2) + rr;
      int p = t0 + rowl;
      if (p < count) {
        size_t off = (size_t)(gb + p) * D;
#pragma unroll
        for (int bj = 0; bj < 4; ++bj) {
          int col = o0 + wc * 64 + bj * 16 + (l & 15);
          EO[off + col] = f2bf(acc[ai][bj][rr]);
        }
      }
    }
  }
}

// ---------------- combine: MOEb[t] = w1*(EO[s1]+b_e1) + w2*(EO[s2]+b_e2)
__global__ __launch_bounds__(256) void combine_kernel(
    const short* __restrict__ EO,
    const int* __restrict__ te1, const int* __restrict__ te2,
    const float* __restrict__ tw1, const float* __restrict__ tw2,
    const int* __restrict__ slot1, const int* __restrict__ slot2,
    const float* __restrict__ exp_b, short* __restrict__ MOEb) {
  int idx = blockIdx.x * 256 + threadIdx.x;   // 6192*96 total
  int t = idx / 96, cg = idx - t * 96;
  int c0 = cg * 8;
  int e1 = te1[t], e2 = te2[t];
  float w1 = tw1[t], w2 = tw2[t];
  short8 a = *(const short8*)(EO + (size_t)slot1[t] * D + c0);
  short8 b = *(const short8*)(EO + (size_t)slot2[t] * D + c0);
  const float* b1 = exp_b + e1 * D + c0;
  const float* b2 = exp_b + e2 * D + c0;
  short8 o;
#pragma unroll
  for (int j = 0; j < 8; ++j)
    o[j] = f2bf(w1 * (bf2f(a[j]) + b1[j]) + w2 * (bf2f(b[j]) + b2[j]));
  *(short8*)(MOEb + (size_t)t * D + c0) = o;
}

// ---------------- QKV projections (MFMA bf16), 64x128 tile, dbuf gload staging
__global__ __launch_bounds__(256) void qkv_kernel(
    const short* __restrict__ MOEb, const short* __restrict__ wT,
    const float* __restrict__ bq, const float* __restrict__ bk,
    const float* __restrict__ bv,
    short* __restrict__ Qb, short* __restrict__ Kb, short* __restrict__ Vb) {
  int id = blockIdx.x;
  int z, r;
  if (id < 384)      { z = 0; r = id; }
  else if (id < 576) { z = 1; r = id - 384; }
  else               { z = 2; r = id - 576; }
  int tb = r / 6, ob = r % 6;
  int o0 = ob * 128;
  int base = (z == 0) ? 0 : MEN_TOK0;
  const short* W = wT + (size_t)z * D * D;
  const float* bias = (z == 0) ? bq : (z == 1) ? bk : bv;
  int tokbase = base + (tb >> 1) * 129 + 1 + (tb & 1) * 64;
  const short* Ag = MOEb + (size_t)tokbase * D;

  __shared__ short8 As[1024];   // 2 bufs x 512
  __shared__ short8 Bs[2048];   // 2 bufs x 1024

  int tid = threadIdx.x;
  int l = tid & 63, w = tid >> 6;
  int wr = w >> 1, wc = w & 1;

  const short* srcA[2];
  const short* srcB[4];
#pragma unroll
  for (int q = 0; q < 2; ++q) {
    int s = (q << 8) + (w << 6) + l;
    int row = s >> 3, cc = s & 7;
    int csrc = (cc ^ (row & 7)) * 8;
    srcA[q] = Ag + (size_t)row * D + csrc;
  }
#pragma unroll
  for (int q = 0; q < 4; ++q) {
    int s = (q << 8) + (w << 6) + l;
    int row = s >> 3, cc = s & 7;
    int csrc = (cc ^ (row & 7)) * 8;
    srcB[q] = W + (size_t)(o0 + row) * D + csrc;
  }

  floatx4 acc[2][4];
#pragma unroll
  for (int ai = 0; ai < 2; ++ai)
#pragma unroll
    for (int bj = 0; bj < 4; ++bj) acc[ai][bj] = (floatx4){0.f, 0.f, 0.f, 0.f};

  // prologue
#pragma unroll
  for (int q = 0; q < 2; ++q) gload16(srcA[q], &As[(q << 8) + (w << 6)]);
#pragma unroll
  for (int q = 0; q < 4; ++q) gload16(srcB[q], &Bs[(q << 8) + (w << 6)]);
  __syncthreads();

  for (int it = 0; it < 12; ++it) {
    int curA = (it & 1) << 9;
    int curB = (it & 1) << 10;
    if (it < 11) {
      int k0n = (it + 1) * 64;
#pragma unroll
      for (int q = 0; q < 2; ++q)
        gload16(srcA[q] + k0n, &As[(curA ^ 512) + (q << 8) + (w << 6)]);
#pragma unroll
      for (int q = 0; q < 4; ++q)
        gload16(srcB[q] + k0n, &Bs[(curB ^ 1024) + (q << 8) + (w << 6)]);
    }
#pragma unroll
    for (int kk = 0; kk < 2; ++kk) {
      int kc = kk * 4 + (l >> 4);
      short8 a[2], bb[4];
#pragma unroll
      for (int ai = 0; ai < 2; ++ai) {
        int ar = wr * 32 + ai * 16 + (l & 15);
        a[ai] = As[curA + (ar << 3) + (kc ^ (ar & 7))];
      }
#pragma unroll
      for (int bj = 0; bj < 4; ++bj) {
        int br = wc * 64 + bj * 16 + (l & 15);
        bb[bj] = Bs[curB + (br << 3) + (kc ^ (br & 7))];
      }
#pragma unroll
      for (int ai = 0; ai < 2; ++ai)
#pragma unroll
        for (int bj = 0; bj < 4; ++bj)
          acc[ai][bj] = __builtin_amdgcn_mfma_f32_16x16x32_bf16(a[ai], bb[bj], acc[ai][bj], 0, 0, 0);
    }
    __syncthreads();
  }

#pragma unroll
  for (int ai = 0; ai < 2; ++ai) {
#pragma unroll
    for (int rr = 0; rr < 4; ++rr) {
      int rowl = wr * 32 + ai * 16 + ((l >> 4) << 2) + rr;
      size_t rglob = (size_t)tb * 64 + rowl;
#pragma unroll
      for (int bj = 0; bj < 4; ++bj) {
        int col = o0 + wc * 64 + bj * 16 + (l & 15);
        float v = acc[ai][bj][rr] + bias[col];
        if (z == 0)      Qb[rglob * D + col] = f2bf(v);
        else if (z == 1) Kb[rglob * D + col] = f2bf(v);
        else             Vb[rglob * D + col] = f2bf(v);
      }
    }
  }
}

__device__ __forceinline__ float blockSum(float v, volatile float* red, int tid) {
#pragma unroll
  for (int off = 32; off > 0; off >>= 1) v += __shfl_down(v, off);
  __syncthreads();
  if ((tid & 63) == 0) red[tid >> 6] = v;
  __syncthreads();
  return red[0] + red[1] + red[2] + red[3];
}

// ---------------- FUSED attention: scores GEMM + softmax + colmean + PV + LN + dots
// one block per (b,n); writes out[b*32+n] directly
__global__ __launch_bounds__(256) void attn_kernel(
    const short* __restrict__ Qb, const short* __restrict__ Kb,
    const short* __restrict__ Vb, const short* __restrict__ MOEb,
    const float* __restrict__ ecls, const float* __restrict__ mcls,
    const float* __restrict__ ln_w, const float* __restrict__ ln_b,
    float* __restrict__ out) {
  int id = blockIdx.x;
  int n = id & 31, b = id >> 5;
  __shared__ short8 Qs[2048];   // 2 bufs x 1024
  __shared__ short8 Ks[2048];
  __shared__ float pb[128];
  __shared__ float red[4];
  int tid = threadIdx.x;
  int l = tid & 63, w = tid >> 6;
  if (tid < 128) pb[tid] = 0.f;

  floatx4 acc[2][8];
#pragma unroll
  for (int i = 0; i < 2; ++i)
#pragma unroll
    for (int j = 0; j < 8; ++j) acc[i][j] = (floatx4){0.f, 0.f, 0.f, 0.f};

  const short* qg = Qb + (size_t)n * 128 * D;
  const short* kg = Kb + (size_t)b * 128 * D;

  const short* srcQ[4];
  const short* srcK[4];
#pragma unroll
  for (int q = 0; q < 4; ++q) {
    int s = (q << 8) + (w << 6) + l;
    int row = s >> 3, cc = s & 7;
    int csrc = (cc ^ (row & 7)) * 8;
    srcQ[q] = qg + (size_t)row * D + csrc;
    srcK[q] = kg + (size_t)row * D + csrc;
  }

  // prologue
#pragma unroll
  for (int q = 0; q < 4; ++q) {
    gload16(srcQ[q], &Qs[(q << 8) + (w << 6)]);
    gload16(srcK[q], &Ks[(q << 8) + (w << 6)]);
  }
  __syncthreads();

  for (int it = 0; it < 12; ++it) {
    int cur = (it & 1) << 10;
    if (it < 11) {
      int nxt = cur ^ 1024;
      int k0n = (it + 1) * 64;
#pragma unroll
      for (int q = 0; q < 4; ++q) {
        gload16(srcQ[q] + k0n, &Qs[nxt + (q << 8) + (w << 6)]);
        gload16(srcK[q] + k0n, &Ks[nxt + (q << 8) + (w << 6)]);
      }
    }
#pragma unroll
    for (int kk = 0; kk < 2; ++kk) {
      int kc = kk * 4 + (l >> 4);
      short8 a[2], bb[8];
#pragma unroll
      for (int i = 0; i < 2; ++i) {
        int ar = w * 32 + i * 16 + (l & 15);
        a[i] = Qs[cur + (ar << 3) + (kc ^ (ar & 7))];
      }
#pragma unroll
      for (int j = 0; j < 8; ++j) {
        int br = j * 16 + (l & 15);
        bb[j] = Ks[cur + (br << 3) + (kc ^ (br & 7))];
      }
#pragma unroll
      for (int i = 0; i < 2; ++i)
#pragma unroll
        for (int j = 0; j < 8; ++j)
          acc[i][j] = __builtin_amdgcn_mfma_f32_16x16x32_bf16(a[i], bb[j], acc[i][j], 0, 0, 0);
    }
    __syncthreads();
  }

  const float scale = 0.03608439182435161f; // 1/sqrt(768)
  float colsum[8];
#pragma unroll
  for (int j = 0; j < 8; ++j) colsum[j] = 0.f;

#pragma unroll
  for (int i = 0; i < 2; ++i) {
#pragma unroll
    for (int r = 0; r < 4; ++r) {
      float mx = -3.0e38f;
#pragma unroll
      for (int j = 0; j < 8; ++j) mx = fmaxf(mx, acc[i][j][r]);
      mx = fmaxf(mx, __shfl_xor(mx, 1));
      mx = fmaxf(mx, __shfl_xor(mx, 2));
      mx = fmaxf(mx, __shfl_xor(mx, 4));
      mx = fmaxf(mx, __shfl_xor(mx, 8));
      float pv[8], sm = 0.f;
#pragma unroll
      for (int j = 0; j < 8; ++j) { pv[j] = __expf((acc[i][j][r] - mx) * scale); sm += pv[j]; }
      sm += __shfl_xor(sm, 1);
      sm += __shfl_xor(sm, 2);
      sm += __shfl_xor(sm, 4);
      sm += __shfl_xor(sm, 8);
      float inv = 1.f / sm;
#pragma unroll
      for (int j = 0; j < 8; ++j) colsum[j] += pv[j] * inv;
    }
  }
#pragma unroll
  for (int j = 0; j < 8; ++j) {
    colsum[j] += __shfl_xor(colsum[j], 16);
    colsum[j] += __shfl_xor(colsum[j], 32);
  }
  if (l < 16) {
#pragma unroll
    for (int j = 0; j < 8; ++j) atomicAdd(&pb[j * 16 + l], colsum[j]);
  }
  __syncthreads();

  // ctx[d] = (1/128) * sum_m pb[m] * V[b,m,d]
  float ctx[3];
  const short* vb = Vb + (size_t)b * 128 * D;
#pragma unroll
  for (int rp = 0; rp < 3; ++rp) {
    int d = tid + rp * 256;
    float a = 0.f;
    for (int m = 0; m < 128; ++m) a += pb[m] * bf2f(vb[(size_t)m * D + d]);
    ctx[rp] = a * (1.f / 128.f);
  }

  // LayerNorm
  float mu = blockSum(ctx[0] + ctx[1] + ctx[2], red, tid) * (1.f / 768.f);
  float vs = 0.f;
#pragma unroll
  for (int rp = 0; rp < 3; ++rp) { float c = ctx[rp] - mu; vs += c * c; }
  float var = blockSum(vs, red, tid) * (1.f / 768.f);
  float rstd = rsqrtf(var + 1e-5f);

  // final dots (ent-cls MoE row = MOEb[n*129])
  const short* em = MOEb + (size_t)(n * 129) * D;
  float g2l_p = 0.f, g2g_p = 0.f;
#pragma unroll
  for (int rp = 0; rp < 3; ++rp) {
    int d = tid + rp * 256;
    float cl = (ctx[rp] - mu) * rstd * ln_w[d] + ln_b[d];
    g2l_p += bf2f(em[d]) * cl;
    g2g_p += mcls[(size_t)b * D + d] * ecls[(size_t)n * D + d];
  }
  float g2l = blockSum(g2l_p, red, tid);
  float g2g = blockSum(g2g_p, red, tid);
  if (tid == 0) out[b * 32 + n] = 0.5f * (g2l + g2g);
}

extern "C" void kernel_launch(void* const* d_in, const int* in_sizes, int n_in,
                              void* d_out, int out_size, void* d_ws, size_t ws_size,
                              hipStream_t stream) {
  const float* ecls   = (const float*)d_in[0];
  const float* etok   = (const float*)d_in[1];
  const float* mcls   = (const float*)d_in[2];
  const float* mtok   = (const float*)d_in[3];
  const float* gate_w = (const float*)d_in[4];
  const float* gate_b = (const float*)d_in[5];
  const float* exp_w  = (const float*)d_in[6];
  const float* exp_b  = (const float*)d_in[7];
  const float* wq     = (const float*)d_in[8];
  const float* bq     = (const float*)d_in[9];
  const float* wk     = (const float*)d_in[10];
  const float* bk     = (const float*)d_in[11];
  const float* wv     = (const float*)d_in[12];
  const float* bv     = (const float*)d_in[13];
  const float* ln_w   = (const float*)d_in[14];
  const float* ln_b   = (const float*)d_in[15];
  float* outp = (float*)d_out;

  char* ws = (char*)d_ws;
  short* Qb    = (short*)(ws + 0);              //  6,291,456 B
  short* Kb    = (short*)(ws + 6291456);        //  3,145,728 B
  short* Vb    = (short*)(ws + 9437184);        //  3,145,728 B (ends 12,582,912)
  short* Xb    = (short*)(ws + 12582912);       //  9,510,912 B (ends 22,093,824)
  short* EO    = (short*)(ws + 22093824);       // 19,021,824 B (ends 41,115,648)
  short* MOEb  = (short*)(ws + 41115648);       //  9,510,912 B (ends 50,626,560)
  short* expwT = (short*)(ws + 50626560);       //  9,437,184 B (ends 60,063,744)
  short* wT    = (short*)(ws + 60063744);       //  3,538,944 B (ends 63,602,688)
  int*   te1   = (int*)  (ws + 63602688);       //     24,768 B each
  int*   te2   = (int*)  (ws + 63627456);
  float* tw1   = (float*)(ws + 63652224);
  float* tw2   = (float*)(ws + 63676992);
  int*   slot1 = (int*)  (ws + 63701760);
  int*   slot2 = (int*)  (ws + 63726528);
  int*   lst_tok = (int*)(ws + 63751296);       //     49,536 B
  int*   cnt   = (int*)  (ws + 63800832);       //         32 B
  int*   basee = (int*)  (ws + 63800864);       //         32 B  (total ~63.8 MB)

  prep_kernel<<<1548 + 1584, 256, 0, stream>>>(ecls, etok, mcls, mtok, gate_w, gate_b,
                                               exp_w, wq, wk, wv,
                                               te1, te2, tw1, tw2, Xb, expwT, wT);
  route_kernel<<<1, 1024, 0, stream>>>(te1, te2, lst_tok, slot1, slot2, cnt, basee);
  moe_kernel<<<49 * 6 * 8, 256, 0, stream>>>(Xb, expwT, cnt, basee, lst_tok, EO);
  combine_kernel<<<2322, 256, 0, stream>>>(EO, te1, te2, tw1, tw2, slot1, slot2,
                                           exp_b, MOEb);
  qkv_kernel<<<768, 256, 0, stream>>>(MOEb, wT, bq, bk, bv, Qb, Kb, Vb);
  attn_kernel<<<512, 256, 0, stream>>>(Qb, Kb, Vb, MOEb, ecls, mcls, ln_w, ln_b, outp);
}

// Round 9
// 133.627 us; speedup vs baseline: 1.1937x; 1.0038x over previous
//
#include <hip/hip_runtime.h>
#include <math.h>

#define D 768
#define NE 8
#define NTOK 6192      // 32*129 + 16*129
#define MEN_TOK0 4128  // 32*129

typedef __attribute__((ext_vector_type(8))) short short8;   // 8 x bf16
typedef __attribute__((ext_vector_type(4))) short short4b;  // 4 x bf16
typedef __attribute__((ext_vector_type(4))) float floatx4;  // MFMA C/D

__device__ __forceinline__ short f2bf(float f) {
  union { float f; unsigned u; } x; x.f = f;
  unsigned r = x.u + 0x7fffu + ((x.u >> 16) & 1u);
  return (short)(r >> 16);
}
__device__ __forceinline__ float bf2f(short s) {
  union { unsigned u; float f; } x; x.u = ((unsigned)(unsigned short)s) << 16;
  return x.f;
}

// async global->LDS 16B: wave-uniform LDS base, per-lane global src
__device__ __forceinline__ void gload16(const short* g, short8* lds_base) {
  __builtin_amdgcn_global_load_lds(
      (const __attribute__((address_space(1))) unsigned int*)g,
      (__attribute__((address_space(3))) unsigned int*)lds_base,
      16, 0, 0);
}

// Map concatenated token index -> source row pointer (virtual concat, no copy).
__device__ __forceinline__ const float* token_row(int t,
    const float* __restrict__ ecls, const float* __restrict__ etok,
    const float* __restrict__ mcls, const float* __restrict__ mtok) {
  if (t < MEN_TOK0) {
    int n = t / 129, s = t - n * 129;
    return (s == 0) ? (ecls + n * D) : (etok + (size_t)(n * 128 + s - 1) * D);
  } else {
    int tm = t - MEN_TOK0;
    int b = tm / 129, s = tm - b * 129;
    return (s == 0) ? (mcls + b * D) : (mtok + (size_t)(b * 128 + s - 1) * D);
  }
}

// ---------------- prep: fused gate (blocks 0..1547) + weight transpose/cvt
__global__ __launch_bounds__(256) void prep_kernel(
    const float* __restrict__ ecls, const float* __restrict__ etok,
    const float* __restrict__ mcls, const float* __restrict__ mtok,
    const float* __restrict__ gate_w, const float* __restrict__ gate_b,
    const float* __restrict__ exp_w, const float* __restrict__ wq,
    const float* __restrict__ wk, const float* __restrict__ wv,
    int* __restrict__ te1, int* __restrict__ te2,
    float* __restrict__ tw1, float* __restrict__ tw2,
    short* __restrict__ Xb, short* __restrict__ expwT, short* __restrict__ wT) {
  __shared__ float tbuf[64][65];
  int bid = blockIdx.x;
  int tid = threadIdx.x;
  if (bid < 1548) {
    int t = bid * 4 + (tid >> 6);
    int lane = tid & 63;
    const float* xr = token_row(t, ecls, etok, mcls, mtok);
    float acc[NE];
#pragma unroll
    for (int e = 0; e < NE; ++e) acc[e] = 0.f;
#pragma unroll
    for (int it = 0; it < 3; ++it) {
      int d0 = lane * 4 + it * 256;
      floatx4 x = *(const floatx4*)(xr + d0);
      short4b xb;
#pragma unroll
      for (int q = 0; q < 4; ++q) {
        xb[q] = f2bf(x[q]);
        float xv = x[q];
#pragma unroll
        for (int e = 0; e < NE; ++e) acc[e] += xv * gate_w[(d0 + q) * NE + e];
      }
      *(short4b*)(Xb + (size_t)t * D + d0) = xb;
    }
#pragma unroll
    for (int e = 0; e < NE; ++e) {
#pragma unroll
      for (int off = 32; off > 0; off >>= 1) acc[e] += __shfl_down(acc[e], off);
    }
    if (lane == 0) {
      float lg[NE];
#pragma unroll
      for (int e = 0; e < NE; ++e) lg[e] = acc[e] + gate_b[e];
      int e1 = 0;
#pragma unroll
      for (int e = 1; e < NE; ++e) if (lg[e] > lg[e1]) e1 = e;
      int e2 = (e1 == 0) ? 1 : 0;
#pragma unroll
      for (int e = 0; e < NE; ++e) {
        if (e != e1 && lg[e] > lg[e2]) e2 = e;
      }
      float w1 = 1.f / (1.f + __expf(lg[e2] - lg[e1]));
      te1[t] = e1; te2[t] = e2;
      tw1[t] = w1; tw2[t] = 1.f - w1;
    }
  } else {
    int zz = bid - 1548;
    int z = zz / 144, rem = zz % 144;
    int k0 = (rem / 12) * 64, o0 = (rem % 12) * 64;
    const float* src; short* dst;
    if (z < 8) { src = exp_w + (size_t)z * D * D; dst = expwT + (size_t)z * D * D; }
    else { src = (z == 8) ? wq : (z == 9) ? wk : wv; dst = wT + (size_t)(z - 8) * D * D; }
    int tx = tid & 63, ty = tid >> 6;
#pragma unroll
    for (int i = 0; i < 16; ++i) {
      int k = i * 4 + ty;
      tbuf[k][tx] = src[(size_t)(k0 + k) * D + o0 + tx];
    }
    __syncthreads();
#pragma unroll
    for (int i = 0; i < 16; ++i) {
      int o = i * 4 + ty;
      dst[(size_t)(o0 + o) * D + k0 + tx] = f2bf(tbuf[tx][o]);
    }
  }
}

// ---------------- route: fused histogram + compaction (single block, LDS atomics)
__global__ __launch_bounds__(1024) void route_kernel(
    const int* __restrict__ te1, const int* __restrict__ te2,
    int* __restrict__ lst_tok, int* __restrict__ slot1, int* __restrict__ slot2,
    int* __restrict__ cnt, int* __restrict__ basee) {
  __shared__ int hist[NE];
  __shared__ int base_s[NE];
  int tid = threadIdx.x;
  if (tid < NE) hist[tid] = 0;
  __syncthreads();
  for (int t = tid; t < NTOK; t += 1024) {
    atomicAdd(&hist[te1[t]], 1);
    atomicAdd(&hist[te2[t]], 1);
  }
  __syncthreads();
  if (tid == 0) {
    int acc = 0;
    for (int e = 0; e < NE; ++e) {
      base_s[e] = acc;
      cnt[e] = hist[e];
      basee[e] = acc;
      acc += hist[e];
    }
  }
  __syncthreads();
  if (tid < NE) hist[tid] = 0;
  __syncthreads();
  for (int t = tid; t < NTOK; t += 1024) {
    int e1 = te1[t], e2 = te2[t];
    int r1 = atomicAdd(&hist[e1], 1);
    int r2 = atomicAdd(&hist[e2], 1);
    int s1 = base_s[e1] + r1;
    int s2 = base_s[e2] + r2;
    slot1[t] = s1; slot2[t] = s2;
    lst_tok[s1] = t; lst_tok[s2] = t;
  }
}

// ---------------- grouped expert GEMM (MFMA bf16), 128x128 tile, BK=32 dbuf
// LDS 32KB -> 4 blocks/CU. swizzle: chunk c ^ ((row>>1)&3)
__global__ __launch_bounds__(256, 4) void moe_kernel(
    const short* __restrict__ Xb, const short* __restrict__ expwT,
    const int* __restrict__ cnt, const int* __restrict__ basee,
    const int* __restrict__ lst_tok, short* __restrict__ EO) {
  int id = blockIdx.x;
  int e = id & 7;
  int r = id >> 3;
  int ob = r % 6;
  int tb = r / 6;
  int count = cnt[e];
  int t0 = tb * 128;
  if (t0 >= count) return;
  int o0 = ob * 128;
  int gb = basee[e];

  __shared__ short8 As[1024];   // 2 bufs x 512 slots (128 rows x 4 chunks)
  __shared__ short8 Bs[1024];
  __shared__ int stok[128];

  int tid = threadIdx.x;
  int l = tid & 63, w = tid >> 6;
  int wr = w >> 1, wc = w & 1;

  if (tid < 128) {
    int p = t0 + tid;
    stok[tid] = lst_tok[gb + (p < count ? p : 0)];
  }
  __syncthreads();

  const short* Bg = expwT + (size_t)e * D * D;
  const short* srcA[2];
  const short* srcB[2];
#pragma unroll
  for (int q = 0; q < 2; ++q) {
    int s = (q << 8) + (w << 6) + l;          // 0..511
    int row = s >> 2, cc = s & 3;
    int csrc = (cc ^ ((row >> 1) & 3)) * 8;
    srcA[q] = Xb + (size_t)stok[row] * D + csrc;
    srcB[q] = Bg + (size_t)(o0 + row) * D + csrc;
  }

  floatx4 acc[4][4];
#pragma unroll
  for (int ai = 0; ai < 4; ++ai)
#pragma unroll
    for (int bj = 0; bj < 4; ++bj) acc[ai][bj] = (floatx4){0.f, 0.f, 0.f, 0.f};

  // prologue: stage k-tile 0 into buffer 0
#pragma unroll
  for (int q = 0; q < 2; ++q) {
    gload16(srcA[q], &As[(q << 8) + (w << 6)]);
    gload16(srcB[q], &Bs[(q << 8) + (w << 6)]);
  }
  __syncthreads();

  for (int it = 0; it < 24; ++it) {
    int cur = (it & 1) << 9;
    if (it < 23) {
      int nxt = cur ^ 512;
      int k0n = (it + 1) * 32;
#pragma unroll
      for (int q = 0; q < 2; ++q) {
        gload16(srcA[q] + k0n, &As[nxt + (q << 8) + (w << 6)]);
        gload16(srcB[q] + k0n, &Bs[nxt + (q << 8) + (w << 6)]);
      }
    }
    int kc = l >> 4;
    short8 a[4], bb[4];
#pragma unroll
    for (int ai = 0; ai < 4; ++ai) {
      int ar = wr * 64 + ai * 16 + (l & 15);
      a[ai] = As[cur + (ar << 2) + (kc ^ ((ar >> 1) & 3))];
    }
#pragma unroll
    for (int bj = 0; bj < 4; ++bj) {
      int br = wc * 64 + bj * 16 + (l & 15);
      bb[bj] = Bs[cur + (br << 2) + (kc ^ ((br >> 1) & 3))];
    }
#pragma unroll
    for (int ai = 0; ai < 4; ++ai)
#pragma unroll
      for (int bj = 0; bj < 4; ++bj)
        acc[ai][bj] = __builtin_amdgcn_mfma_f32_16x16x32_bf16(a[ai], bb[bj], acc[ai][bj], 0, 0, 0);
    __syncthreads();
  }

  // epilogue: C/D layout col=lane&15, row=(lane>>4)*4+reg
#pragma unroll
  for (int ai = 0; ai < 4; ++ai) {
#pragma unroll
    for (int rr = 0; rr < 4; ++rr) {
      int rowl = wr * 64 + ai * 16 + ((l >> 4) << 2) + rr;
      int p = t0 + rowl;
      if (p < count) {
        size_t off = (size_t)(gb + p) * D;
#pragma unroll
        for (int bj = 0; bj < 4; ++bj) {
          int col = o0 + wc * 64 + bj * 16 + (l & 15);
          EO[off + col] = f2bf(acc[ai][bj][rr]);
        }
      }
    }
  }
}

// ---------------- combine: MOEb[t] = w1*(EO[s1]+b_e1) + w2*(EO[s2]+b_e2)
__global__ __launch_bounds__(256) void combine_kernel(
    const short* __restrict__ EO,
    const int* __restrict__ te1, const int* __restrict__ te2,
    const float* __restrict__ tw1, const float* __restrict__ tw2,
    const int* __restrict__ slot1, const int* __restrict__ slot2,
    const float* __restrict__ exp_b, short* __restrict__ MOEb) {
  int idx = blockIdx.x * 256 + threadIdx.x;   // 6192*96 total
  int t = idx / 96, cg = idx - t * 96;
  int c0 = cg * 8;
  int e1 = te1[t], e2 = te2[t];
  float w1 = tw1[t], w2 = tw2[t];
  short8 a = *(const short8*)(EO + (size_t)slot1[t] * D + c0);
  short8 b = *(const short8*)(EO + (size_t)slot2[t] * D + c0);
  const float* b1 = exp_b + e1 * D + c0;
  const float* b2 = exp_b + e2 * D + c0;
  short8 o;
#pragma unroll
  for (int j = 0; j < 8; ++j)
    o[j] = f2bf(w1 * (bf2f(a[j]) + b1[j]) + w2 * (bf2f(b[j]) + b2[j]));
  *(short8*)(MOEb + (size_t)t * D + c0) = o;
}

// ---------------- QKV projections (MFMA bf16), 64x128 tile, BK=32 dbuf
// LDS 24KB -> 6 blocks/CU
__global__ __launch_bounds__(256, 6) void qkv_kernel(
    const short* __restrict__ MOEb, const short* __restrict__ wT,
    const float* __restrict__ bq, const float* __restrict__ bk,
    const float* __restrict__ bv,
    short* __restrict__ Qb, short* __restrict__ Kb, short* __restrict__ Vb) {
  int id = blockIdx.x;
  int z, r;
  if (id < 384)      { z = 0; r = id; }
  else if (id < 576) { z = 1; r = id - 384; }
  else               { z = 2; r = id - 576; }
  int tb = r / 6, ob = r % 6;
  int o0 = ob * 128;
  int base = (z == 0) ? 0 : MEN_TOK0;
  const short* W = wT + (size_t)z * D * D;
  const float* bias = (z == 0) ? bq : (z == 1) ? bk : bv;
  int tokbase = base + (tb >> 1) * 129 + 1 + (tb & 1) * 64;
  const short* Ag = MOEb + (size_t)tokbase * D;

  __shared__ short8 As[512];    // 2 bufs x 256 slots (64 rows x 4 chunks)
  __shared__ short8 Bs[1024];   // 2 bufs x 512 slots

  int tid = threadIdx.x;
  int l = tid & 63, w = tid >> 6;
  int wr = w >> 1, wc = w & 1;

  const short* srcA;
  const short* srcB[2];
  {
    int s = tid;                               // 0..255
    int row = s >> 2, cc = s & 3;
    int csrc = (cc ^ ((row >> 1) & 3)) * 8;
    srcA = Ag + (size_t)row * D + csrc;
  }
#pragma unroll
  for (int q = 0; q < 2; ++q) {
    int s = (q << 8) + tid;                    // 0..511
    int row = s >> 2, cc = s & 3;
    int csrc = (cc ^ ((row >> 1) & 3)) * 8;
    srcB[q] = W + (size_t)(o0 + row) * D + csrc;
  }

  floatx4 acc[2][4];
#pragma unroll
  for (int ai = 0; ai < 2; ++ai)
#pragma unroll
    for (int bj = 0; bj < 4; ++bj) acc[ai][bj] = (floatx4){0.f, 0.f, 0.f, 0.f};

  // prologue
  gload16(srcA, &As[w << 6]);
#pragma unroll
  for (int q = 0; q < 2; ++q) gload16(srcB[q], &Bs[(q << 8) + (w << 6)]);
  __syncthreads();

  for (int it = 0; it < 24; ++it) {
    int curA = (it & 1) << 8;
    int curB = (it & 1) << 9;
    if (it < 23) {
      int k0n = (it + 1) * 32;
      gload16(srcA + k0n, &As[(curA ^ 256) + (w << 6)]);
#pragma unroll
      for (int q = 0; q < 2; ++q)
        gload16(srcB[q] + k0n, &Bs[(curB ^ 512) + (q << 8) + (w << 6)]);
    }
    int kc = l >> 4;
    short8 a[2], bb[4];
#pragma unroll
    for (int ai = 0; ai < 2; ++ai) {
      int ar = wr * 32 + ai * 16 + (l & 15);
      a[ai] = As[curA + (ar << 2) + (kc ^ ((ar >> 1) & 3))];
    }
#pragma unroll
    for (int bj = 0; bj < 4; ++bj) {
      int br = wc * 64 + bj * 16 + (l & 15);
      bb[bj] = Bs[curB + (br << 2) + (kc ^ ((br >> 1) & 3))];
    }
#pragma unroll
    for (int ai = 0; ai < 2; ++ai)
#pragma unroll
      for (int bj = 0; bj < 4; ++bj)
        acc[ai][bj] = __builtin_amdgcn_mfma_f32_16x16x32_bf16(a[ai], bb[bj], acc[ai][bj], 0, 0, 0);
    __syncthreads();
  }

#pragma unroll
  for (int ai = 0; ai < 2; ++ai) {
#pragma unroll
    for (int rr = 0; rr < 4; ++rr) {
      int rowl = wr * 32 + ai * 16 + ((l >> 4) << 2) + rr;
      size_t rglob = (size_t)tb * 64 + rowl;
#pragma unroll
      for (int bj = 0; bj < 4; ++bj) {
        int col = o0 + wc * 64 + bj * 16 + (l & 15);
        float v = acc[ai][bj][rr] + bias[col];
        if (z == 0)      Qb[rglob * D + col] = f2bf(v);
        else if (z == 1) Kb[rglob * D + col] = f2bf(v);
        else             Vb[rglob * D + col] = f2bf(v);
      }
    }
  }
}

__device__ __forceinline__ float blockSum(float v, volatile float* red, int tid) {
#pragma unroll
  for (int off = 32; off > 0; off >>= 1) v += __shfl_down(v, off);
  __syncthreads();
  if ((tid & 63) == 0) red[tid >> 6] = v;
  __syncthreads();
  return red[0] + red[1] + red[2] + red[3];
}

// ---------------- FUSED attention: scores GEMM + softmax + colmean + PV + LN + dots
// BK=32 dbuf, LDS ~33KB -> 4 blocks/CU. one block per (b,n)
__global__ __launch_bounds__(256, 4) void attn_kernel(
    const short* __restrict__ Qb, const short* __restrict__ Kb,
    const short* __restrict__ Vb, const short* __restrict__ MOEb,
    const float* __restrict__ ecls, const float* __restrict__ mcls,
    const float* __restrict__ ln_w, const float* __restrict__ ln_b,
    float* __restrict__ out) {
  int id = blockIdx.x;
  int n = id & 31, b = id >> 5;
  __shared__ short8 Qs[1024];   // 2 bufs x 512 slots (128 rows x 4 chunks)
  __shared__ short8 Ks[1024];
  __shared__ float pb[128];
  __shared__ float red[4];
  int tid = threadIdx.x;
  int l = tid & 63, w = tid >> 6;
  if (tid < 128) pb[tid] = 0.f;

  floatx4 acc[2][8];
#pragma unroll
  for (int i = 0; i < 2; ++i)
#pragma unroll
    for (int j = 0; j < 8; ++j) acc[i][j] = (floatx4){0.f, 0.f, 0.f, 0.f};

  const short* qg = Qb + (size_t)n * 128 * D;
  const short* kg = Kb + (size_t)b * 128 * D;

  const short* srcQ[2];
  const short* srcK[2];
#pragma unroll
  for (int q = 0; q < 2; ++q) {
    int s = (q << 8) + tid;                    // 0..511
    int row = s >> 2, cc = s & 3;
    int csrc = (cc ^ ((row >> 1) & 3)) * 8;
    srcQ[q] = qg + (size_t)row * D + csrc;
    srcK[q] = kg + (size_t)row * D + csrc;
  }

  // prologue
#pragma unroll
  for (int q = 0; q < 2; ++q) {
    gload16(srcQ[q], &Qs[(q << 8) + (w << 6)]);
    gload16(srcK[q], &Ks[(q << 8) + (w << 6)]);
  }
  __syncthreads();

  for (int it = 0; it < 24; ++it) {
    int cur = (it & 1) << 9;
    if (it < 23) {
      int nxt = cur ^ 512;
      int k0n = (it + 1) * 32;
#pragma unroll
      for (int q = 0; q < 2; ++q) {
        gload16(srcQ[q] + k0n, &Qs[nxt + (q << 8) + (w << 6)]);
        gload16(srcK[q] + k0n, &Ks[nxt + (q << 8) + (w << 6)]);
      }
    }
    int kc = l >> 4;
    short8 a[2], bb[8];
#pragma unroll
    for (int i = 0; i < 2; ++i) {
      int ar = w * 32 + i * 16 + (l & 15);
      a[i] = Qs[cur + (ar << 2) + (kc ^ ((ar >> 1) & 3))];
    }
#pragma unroll
    for (int j = 0; j < 8; ++j) {
      int br = j * 16 + (l & 15);
      bb[j] = Ks[cur + (br << 2) + (kc ^ ((br >> 1) & 3))];
    }
#pragma unroll
    for (int i = 0; i < 2; ++i)
#pragma unroll
      for (int j = 0; j < 8; ++j)
        acc[i][j] = __builtin_amdgcn_mfma_f32_16x16x32_bf16(a[i], bb[j], acc[i][j], 0, 0, 0);
    __syncthreads();
  }

  const float scale = 0.03608439182435161f; // 1/sqrt(768)
  float colsum[8];
#pragma unroll
  for (int j = 0; j < 8; ++j) colsum[j] = 0.f;

#pragma unroll
  for (int i = 0; i < 2; ++i) {
#pragma unroll
    for (int r = 0; r < 4; ++r) {
      float mx = -3.0e38f;
#pragma unroll
      for (int j = 0; j < 8; ++j) mx = fmaxf(mx, acc[i][j][r]);
      mx = fmaxf(mx, __shfl_xor(mx, 1));
      mx = fmaxf(mx, __shfl_xor(mx, 2));
      mx = fmaxf(mx, __shfl_xor(mx, 4));
      mx = fmaxf(mx, __shfl_xor(mx, 8));
      float pv[8], sm = 0.f;
#pragma unroll
      for (int j = 0; j < 8; ++j) { pv[j] = __expf((acc[i][j][r] - mx) * scale); sm += pv[j]; }
      sm += __shfl_xor(sm, 1);
      sm += __shfl_xor(sm, 2);
      sm += __shfl_xor(sm, 4);
      sm += __shfl_xor(sm, 8);
      float inv = 1.f / sm;
#pragma unroll
      for (int j = 0; j < 8; ++j) colsum[j] += pv[j] * inv;
    }
  }
#pragma unroll
  for (int j = 0; j < 8; ++j) {
    colsum[j] += __shfl_xor(colsum[j], 16);
    colsum[j] += __shfl_xor(colsum[j], 32);
  }
  if (l < 16) {
#pragma unroll
    for (int j = 0; j < 8; ++j) atomicAdd(&pb[j * 16 + l], colsum[j]);
  }
  __syncthreads();

  // ctx[d] = (1/128) * sum_m pb[m] * V[b,m,d]
  float ctx[3];
  const short* vb = Vb + (size_t)b * 128 * D;
#pragma unroll
  for (int rp = 0; rp < 3; ++rp) {
    int d = tid + rp * 256;
    float a = 0.f;
    for (int m = 0; m < 128; ++m) a += pb[m] * bf2f(vb[(size_t)m * D + d]);
    ctx[rp] = a * (1.f / 128.f);
  }

  // LayerNorm
  float mu = blockSum(ctx[0] + ctx[1] + ctx[2], red, tid) * (1.f / 768.f);
  float vs = 0.f;
#pragma unroll
  for (int rp = 0; rp < 3; ++rp) { float c = ctx[rp] - mu; vs += c * c; }
  float var = blockSum(vs, red, tid) * (1.f / 768.f);
  float rstd = rsqrtf(var + 1e-5f);

  // final dots (ent-cls MoE row = MOEb[n*129])
  const short* em = MOEb + (size_t)(n * 129) * D;
  float g2l_p = 0.f, g2g_p = 0.f;
#pragma unroll
  for (int rp = 0; rp < 3; ++rp) {
    int d = tid + rp * 256;
    float cl = (ctx[rp] - mu) * rstd * ln_w[d] + ln_b[d];
    g2l_p += bf2f(em[d]) * cl;
    g2g_p += mcls[(size_t)b * D + d] * ecls[(size_t)n * D + d];
  }
  float g2l = blockSum(g2l_p, red, tid);
  float g2g = blockSum(g2g_p, red, tid);
  if (tid == 0) out[b * 32 + n] = 0.5f * (g2l + g2g);
}

extern "C" void kernel_launch(void* const* d_in, const int* in_sizes, int n_in,
                              void* d_out, int out_size, void* d_ws, size_t ws_size,
                              hipStream_t stream) {
  const float* ecls   = (const float*)d_in[0];
  const float* etok   = (const float*)d_in[1];
  const float* mcls   = (const float*)d_in[2];
  const float* mtok   = (const float*)d_in[3];
  const float* gate_w = (const float*)d_in[4];
  const float* gate_b = (const float*)d_in[5];
  const float* exp_w  = (const float*)d_in[6];
  const float* exp_b  = (const float*)d_in[7];
  const float* wq     = (const float*)d_in[8];
  const float* bq     = (const float*)d_in[9];
  const float* wk     = (const float*)d_in[10];
  const float* bk     = (const float*)d_in[11];
  const float* wv     = (const float*)d_in[12];
  const float* bv     = (const float*)d_in[13];
  const float* ln_w   = (const float*)d_in[14];
  const float* ln_b   = (const float*)d_in[15];
  float* outp = (float*)d_out;

  char* ws = (char*)d_ws;
  short* Qb    = (short*)(ws + 0);              //  6,291,456 B
  short* Kb    = (short*)(ws + 6291456);        //  3,145,728 B
  short* Vb    = (short*)(ws + 9437184);        //  3,145,728 B (ends 12,582,912)
  short* Xb    = (short*)(ws + 12582912);       //  9,510,912 B (ends 22,093,824)
  short* EO    = (short*)(ws + 22093824);       // 19,021,824 B (ends 41,115,648)
  short* MOEb  = (short*)(ws + 41115648);       //  9,510,912 B (ends 50,626,560)
  short* expwT = (short*)(ws + 50626560);       //  9,437,184 B (ends 60,063,744)
  short* wT    = (short*)(ws + 60063744);       //  3,538,944 B (ends 63,602,688)
  int*   te1   = (int*)  (ws + 63602688);       //     24,768 B each
  int*   te2   = (int*)  (ws + 63627456);
  float* tw1   = (float*)(ws + 63652224);
  float* tw2   = (float*)(ws + 63676992);
  int*   slot1 = (int*)  (ws + 63701760);
  int*   slot2 = (int*)  (ws + 63726528);
  int*   lst_tok = (int*)(ws + 63751296);       //     49,536 B
  int*   cnt   = (int*)  (ws + 63800832);       //         32 B
  int*   basee = (int*)  (ws + 63800864);       //         32 B  (total ~63.8 MB)

  prep_kernel<<<1548 + 1584, 256, 0, stream>>>(ecls, etok, mcls, mtok, gate_w, gate_b,
                                               exp_w, wq, wk, wv,
                                               te1, te2, tw1, tw2, Xb, expwT, wT);
  route_kernel<<<1, 1024, 0, stream>>>(te1, te2, lst_tok, slot1, slot2, cnt, basee);
  moe_kernel<<<49 * 6 * 8, 256, 0, stream>>>(Xb, expwT, cnt, basee, lst_tok, EO);
  combine_kernel<<<2322, 256, 0, stream>>>(EO, te1, te2, tw1, tw2, slot1, slot2,
                                           exp_b, MOEb);
  qkv_kernel<<<768, 256, 0, stream>>>(MOEb, wT, bq, bk, bv, Qb, Kb, Vb);
  attn_kernel<<<512, 256, 0, stream>>>(Qb, Kb, Vb, MOEb, ecls, mcls, ln_w, ln_b, outp);
}

// Round 10
// 124.912 us; speedup vs baseline: 1.2769x; 1.0698x over previous
//
#include <hip/hip_runtime.h>
#include <math.h>

#define D 768
#define NE 8
#define NTOK 6192      // 32*129 + 16*129
#define MEN_TOK0 4128  // 32*129

typedef __attribute__((ext_vector_type(8))) short short8;   // 8 x bf16
typedef __attribute__((ext_vector_type(4))) short short4b;  // 4 x bf16
typedef __attribute__((ext_vector_type(4))) float floatx4;  // MFMA C/D

__device__ __forceinline__ short f2bf(float f) {
  union { float f; unsigned u; } x; x.f = f;
  unsigned r = x.u + 0x7fffu + ((x.u >> 16) & 1u);
  return (short)(r >> 16);
}
__device__ __forceinline__ float bf2f(short s) {
  union { unsigned u; float f; } x; x.u = ((unsigned)(unsigned short)s) << 16;
  return x.f;
}

// async global->LDS 16B: wave-uniform LDS base, per-lane global src
__device__ __forceinline__ void gload16(const short* g, short8* lds_base) {
  __builtin_amdgcn_global_load_lds(
      (const __attribute__((address_space(1))) unsigned int*)g,
      (__attribute__((address_space(3))) unsigned int*)lds_base,
      16, 0, 0);
}

// Map concatenated token index -> source row pointer (virtual concat, no copy).
__device__ __forceinline__ const float* token_row(int t,
    const float* __restrict__ ecls, const float* __restrict__ etok,
    const float* __restrict__ mcls, const float* __restrict__ mtok) {
  if (t < MEN_TOK0) {
    int n = t / 129, s = t - n * 129;
    return (s == 0) ? (ecls + n * D) : (etok + (size_t)(n * 128 + s - 1) * D);
  } else {
    int tm = t - MEN_TOK0;
    int b = tm / 129, s = tm - b * 129;
    return (s == 0) ? (mcls + b * D) : (mtok + (size_t)(b * 128 + s - 1) * D);
  }
}

// ---------------- prep: fused gate (blocks 0..1547) + weight transpose/cvt
__global__ __launch_bounds__(256) void prep_kernel(
    const float* __restrict__ ecls, const float* __restrict__ etok,
    const float* __restrict__ mcls, const float* __restrict__ mtok,
    const float* __restrict__ gate_w, const float* __restrict__ gate_b,
    const float* __restrict__ exp_w, const float* __restrict__ wq,
    const float* __restrict__ wk, const float* __restrict__ wv,
    int* __restrict__ te1, int* __restrict__ te2,
    float* __restrict__ tw1, float* __restrict__ tw2,
    short* __restrict__ Xb, short* __restrict__ expwT, short* __restrict__ wT) {
  __shared__ float tbuf[64][65];
  int bid = blockIdx.x;
  int tid = threadIdx.x;
  if (bid < 1548) {
    int t = bid * 4 + (tid >> 6);
    int lane = tid & 63;
    const float* xr = token_row(t, ecls, etok, mcls, mtok);
    float acc[NE];
#pragma unroll
    for (int e = 0; e < NE; ++e) acc[e] = 0.f;
#pragma unroll
    for (int it = 0; it < 3; ++it) {
      int d0 = lane * 4 + it * 256;
      floatx4 x = *(const floatx4*)(xr + d0);
      short4b xb;
#pragma unroll
      for (int q = 0; q < 4; ++q) {
        xb[q] = f2bf(x[q]);
        float xv = x[q];
#pragma unroll
        for (int e = 0; e < NE; ++e) acc[e] += xv * gate_w[(d0 + q) * NE + e];
      }
      *(short4b*)(Xb + (size_t)t * D + d0) = xb;
    }
#pragma unroll
    for (int e = 0; e < NE; ++e) {
#pragma unroll
      for (int off = 32; off > 0; off >>= 1) acc[e] += __shfl_down(acc[e], off);
    }
    if (lane == 0) {
      float lg[NE];
#pragma unroll
      for (int e = 0; e < NE; ++e) lg[e] = acc[e] + gate_b[e];
      int e1 = 0;
#pragma unroll
      for (int e = 1; e < NE; ++e) if (lg[e] > lg[e1]) e1 = e;
      int e2 = (e1 == 0) ? 1 : 0;
#pragma unroll
      for (int e = 0; e < NE; ++e) {
        if (e != e1 && lg[e] > lg[e2]) e2 = e;
      }
      float w1 = 1.f / (1.f + __expf(lg[e2] - lg[e1]));
      te1[t] = e1; te2[t] = e2;
      tw1[t] = w1; tw2[t] = 1.f - w1;
    }
  } else {
    int zz = bid - 1548;
    int z = zz / 144, rem = zz % 144;
    int k0 = (rem / 12) * 64, o0 = (rem % 12) * 64;
    const float* src; short* dst;
    if (z < 8) { src = exp_w + (size_t)z * D * D; dst = expwT + (size_t)z * D * D; }
    else { src = (z == 8) ? wq : (z == 9) ? wk : wv; dst = wT + (size_t)(z - 8) * D * D; }
    int tx = tid & 63, ty = tid >> 6;
#pragma unroll
    for (int i = 0; i < 16; ++i) {
      int k = i * 4 + ty;
      tbuf[k][tx] = src[(size_t)(k0 + k) * D + o0 + tx];
    }
    __syncthreads();
#pragma unroll
    for (int i = 0; i < 16; ++i) {
      int o = i * 4 + ty;
      dst[(size_t)(o0 + o) * D + k0 + tx] = f2bf(tbuf[tx][o]);
    }
  }
}

// ---------------- route: fused histogram + compaction (single block, LDS atomics)
__global__ __launch_bounds__(1024) void route_kernel(
    const int* __restrict__ te1, const int* __restrict__ te2,
    int* __restrict__ lst_tok, int* __restrict__ slot1, int* __restrict__ slot2,
    int* __restrict__ cnt, int* __restrict__ basee) {
  __shared__ int hist[NE];
  __shared__ int base_s[NE];
  int tid = threadIdx.x;
  if (tid < NE) hist[tid] = 0;
  __syncthreads();
  for (int t = tid; t < NTOK; t += 1024) {
    atomicAdd(&hist[te1[t]], 1);
    atomicAdd(&hist[te2[t]], 1);
  }
  __syncthreads();
  if (tid == 0) {
    int acc = 0;
    for (int e = 0; e < NE; ++e) {
      base_s[e] = acc;
      cnt[e] = hist[e];
      basee[e] = acc;
      acc += hist[e];
    }
  }
  __syncthreads();
  if (tid < NE) hist[tid] = 0;
  __syncthreads();
  for (int t = tid; t < NTOK; t += 1024) {
    int e1 = te1[t], e2 = te2[t];
    int r1 = atomicAdd(&hist[e1], 1);
    int r2 = atomicAdd(&hist[e2], 1);
    int s1 = base_s[e1] + r1;
    int s2 = base_s[e2] + r2;
    slot1[t] = s1; slot2[t] = s2;
    lst_tok[s1] = t; lst_tok[s2] = t;
  }
}

// ---------------- grouped expert GEMM (MFMA bf16), 128x128 tile, BK=32 dbuf
// 512 threads / 8 waves (4 row-groups x 2 col-groups of 32x64)
__global__ __launch_bounds__(512, 4) void moe_kernel(
    const short* __restrict__ Xb, const short* __restrict__ expwT,
    const int* __restrict__ cnt, const int* __restrict__ basee,
    const int* __restrict__ lst_tok, short* __restrict__ EO) {
  int id = blockIdx.x;
  int e = id & 7;
  int r = id >> 3;
  int ob = r % 6;
  int tb = r / 6;
  int count = cnt[e];
  int t0 = tb * 128;
  if (t0 >= count) return;
  int o0 = ob * 128;
  int gb = basee[e];

  __shared__ short8 As[1024];   // 2 bufs x 512 slots (128 rows x 4 chunks)
  __shared__ short8 Bs[1024];
  __shared__ int stok[128];

  int tid = threadIdx.x;
  int l = tid & 63, w = tid >> 6;   // w 0..7
  int wr = w >> 1, wc = w & 1;

  if (tid < 128) {
    int p = t0 + tid;
    stok[tid] = lst_tok[gb + (p < count ? p : 0)];
  }
  __syncthreads();

  const short* Bg = expwT + (size_t)e * D * D;
  int srow = tid >> 2, scc = tid & 3;
  int csrc = (scc ^ ((srow >> 1) & 3)) * 8;
  const short* srcA = Xb + (size_t)stok[srow] * D + csrc;
  const short* srcB = Bg + (size_t)(o0 + srow) * D + csrc;

  floatx4 acc[2][4];
#pragma unroll
  for (int ai = 0; ai < 2; ++ai)
#pragma unroll
    for (int bj = 0; bj < 4; ++bj) acc[ai][bj] = (floatx4){0.f, 0.f, 0.f, 0.f};

  // prologue: stage k-tile 0 into buffer 0 (1 slot/thread/tensor)
  gload16(srcA, &As[w << 6]);
  gload16(srcB, &Bs[w << 6]);
  __syncthreads();

  for (int it = 0; it < 24; ++it) {
    int cur = (it & 1) << 9;
    if (it < 23) {
      int k0n = (it + 1) * 32;
      gload16(srcA + k0n, &As[(cur ^ 512) + (w << 6)]);
      gload16(srcB + k0n, &Bs[(cur ^ 512) + (w << 6)]);
    }
    int kc = l >> 4;
    short8 a[2], bb[4];
#pragma unroll
    for (int ai = 0; ai < 2; ++ai) {
      int ar = wr * 32 + ai * 16 + (l & 15);
      a[ai] = As[cur + (ar << 2) + (kc ^ ((ar >> 1) & 3))];
    }
#pragma unroll
    for (int bj = 0; bj < 4; ++bj) {
      int br = wc * 64 + bj * 16 + (l & 15);
      bb[bj] = Bs[cur + (br << 2) + (kc ^ ((br >> 1) & 3))];
    }
#pragma unroll
    for (int ai = 0; ai < 2; ++ai)
#pragma unroll
      for (int bj = 0; bj < 4; ++bj)
        acc[ai][bj] = __builtin_amdgcn_mfma_f32_16x16x32_bf16(a[ai], bb[bj], acc[ai][bj], 0, 0, 0);
    __syncthreads();
  }

  // epilogue: C/D layout col=lane&15, row=(lane>>4)*4+reg
#pragma unroll
  for (int ai = 0; ai < 2; ++ai) {
#pragma unroll
    for (int rr = 0; rr < 4; ++rr) {
      int rowl = wr * 32 + ai * 16 + ((l >> 4) << 2) + rr;
      int p = t0 + rowl;
      if (p < count) {
        size_t off = (size_t)(gb + p) * D;
#pragma unroll
        for (int bj = 0; bj < 4; ++bj) {
          int col = o0 + wc * 64 + bj * 16 + (l & 15);
          EO[off + col] = f2bf(acc[ai][bj][rr]);
        }
      }
    }
  }
}

// ---------------- combine: MOEb[t] = w1*(EO[s1]+b_e1) + w2*(EO[s2]+b_e2)
__global__ __launch_bounds__(256) void combine_kernel(
    const short* __restrict__ EO,
    const int* __restrict__ te1, const int* __restrict__ te2,
    const float* __restrict__ tw1, const float* __restrict__ tw2,
    const int* __restrict__ slot1, const int* __restrict__ slot2,
    const float* __restrict__ exp_b, short* __restrict__ MOEb) {
  int idx = blockIdx.x * 256 + threadIdx.x;   // 6192*96 total
  int t = idx / 96, cg = idx - t * 96;
  int c0 = cg * 8;
  int e1 = te1[t], e2 = te2[t];
  float w1 = tw1[t], w2 = tw2[t];
  short8 a = *(const short8*)(EO + (size_t)slot1[t] * D + c0);
  short8 b = *(const short8*)(EO + (size_t)slot2[t] * D + c0);
  const float* b1 = exp_b + e1 * D + c0;
  const float* b2 = exp_b + e2 * D + c0;
  short8 o;
#pragma unroll
  for (int j = 0; j < 8; ++j)
    o[j] = f2bf(w1 * (bf2f(a[j]) + b1[j]) + w2 * (bf2f(b[j]) + b2[j]));
  *(short8*)(MOEb + (size_t)t * D + c0) = o;
}

// ---------------- QKV projections (MFMA bf16), 64x128 tile, BK=32 dbuf
// 512 threads / 8 waves (4 row-groups x 2 col-groups of 16x64)
__global__ __launch_bounds__(512, 4) void qkv_kernel(
    const short* __restrict__ MOEb, const short* __restrict__ wT,
    const float* __restrict__ bq, const float* __restrict__ bk,
    const float* __restrict__ bv,
    short* __restrict__ Qb, short* __restrict__ Kb, short* __restrict__ Vb) {
  int id = blockIdx.x;
  int z, r;
  if (id < 384)      { z = 0; r = id; }
  else if (id < 576) { z = 1; r = id - 384; }
  else               { z = 2; r = id - 576; }
  int tb = r / 6, ob = r % 6;
  int o0 = ob * 128;
  int base = (z == 0) ? 0 : MEN_TOK0;
  const short* W = wT + (size_t)z * D * D;
  const float* bias = (z == 0) ? bq : (z == 1) ? bk : bv;
  int tokbase = base + (tb >> 1) * 129 + 1 + (tb & 1) * 64;
  const short* Ag = MOEb + (size_t)tokbase * D;

  __shared__ short8 As[512];    // 2 bufs x 256 slots (64 rows x 4 chunks)
  __shared__ short8 Bs[1024];   // 2 bufs x 512 slots

  int tid = threadIdx.x;
  int l = tid & 63, w = tid >> 6;   // w 0..7
  int wr = w >> 1, wc = w & 1;

  int srow = tid >> 2, scc = tid & 3;
  int csrc = (scc ^ ((srow >> 1) & 3)) * 8;
  const short* srcA = Ag + (size_t)(srow & 63) * D + csrc;   // used only by w<4 (srow<64)
  const short* srcB = W + (size_t)(o0 + srow) * D + csrc;

  floatx4 acc[4];
#pragma unroll
  for (int bj = 0; bj < 4; ++bj) acc[bj] = (floatx4){0.f, 0.f, 0.f, 0.f};

  // prologue
  if (w < 4) gload16(srcA, &As[w << 6]);
  gload16(srcB, &Bs[w << 6]);
  __syncthreads();

  for (int it = 0; it < 24; ++it) {
    int curA = (it & 1) << 8;
    int curB = (it & 1) << 9;
    if (it < 23) {
      int k0n = (it + 1) * 32;
      if (w < 4) gload16(srcA + k0n, &As[(curA ^ 256) + (w << 6)]);
      gload16(srcB + k0n, &Bs[(curB ^ 512) + (w << 6)]);
    }
    int kc = l >> 4;
    int ar = wr * 16 + (l & 15);
    short8 a = As[curA + (ar << 2) + (kc ^ ((ar >> 1) & 3))];
    short8 bb[4];
#pragma unroll
    for (int bj = 0; bj < 4; ++bj) {
      int br = wc * 64 + bj * 16 + (l & 15);
      bb[bj] = Bs[curB + (br << 2) + (kc ^ ((br >> 1) & 3))];
    }
#pragma unroll
    for (int bj = 0; bj < 4; ++bj)
      acc[bj] = __builtin_amdgcn_mfma_f32_16x16x32_bf16(a, bb[bj], acc[bj], 0, 0, 0);
    __syncthreads();
  }

#pragma unroll
  for (int rr = 0; rr < 4; ++rr) {
    int rowl = wr * 16 + ((l >> 4) << 2) + rr;
    size_t rglob = (size_t)tb * 64 + rowl;
#pragma unroll
    for (int bj = 0; bj < 4; ++bj) {
      int col = o0 + wc * 64 + bj * 16 + (l & 15);
      float v = acc[bj][rr] + bias[col];
      if (z == 0)      Qb[rglob * D + col] = f2bf(v);
      else if (z == 1) Kb[rglob * D + col] = f2bf(v);
      else             Vb[rglob * D + col] = f2bf(v);
    }
  }
}

__device__ __forceinline__ float blockSum512(float v, volatile float* red, int tid) {
#pragma unroll
  for (int off = 32; off > 0; off >>= 1) v += __shfl_down(v, off);
  __syncthreads();
  if ((tid & 63) == 0) red[tid >> 6] = v;
  __syncthreads();
  float s = 0.f;
#pragma unroll
  for (int i = 0; i < 8; ++i) s += red[i];
  return s;
}

// ---------------- FUSED attention: scores GEMM + softmax + colmean + PV + LN + dots
// 512 threads / 8 waves, each wave owns one 16-row block. one block per (b,n)
__global__ __launch_bounds__(512, 4) void attn_kernel(
    const short* __restrict__ Qb, const short* __restrict__ Kb,
    const short* __restrict__ Vb, const short* __restrict__ MOEb,
    const float* __restrict__ ecls, const float* __restrict__ mcls,
    const float* __restrict__ ln_w, const float* __restrict__ ln_b,
    float* __restrict__ out) {
  int id = blockIdx.x;
  int n = id & 31, b = id >> 5;
  __shared__ short8 Qs[1024];   // 2 bufs x 512 slots (128 rows x 4 chunks)
  __shared__ short8 Ks[1024];
  __shared__ float pb[128];
  __shared__ float red[8];
  int tid = threadIdx.x;
  int l = tid & 63, w = tid >> 6;   // w 0..7
  if (tid < 128) pb[tid] = 0.f;

  floatx4 acc[8];
#pragma unroll
  for (int j = 0; j < 8; ++j) acc[j] = (floatx4){0.f, 0.f, 0.f, 0.f};

  const short* qg = Qb + (size_t)n * 128 * D;
  const short* kg = Kb + (size_t)b * 128 * D;

  int srow = tid >> 2, scc = tid & 3;
  int csrc = (scc ^ ((srow >> 1) & 3)) * 8;
  const short* srcQ = qg + (size_t)srow * D + csrc;
  const short* srcK = kg + (size_t)srow * D + csrc;

  // prologue (1 slot/thread/tensor)
  gload16(srcQ, &Qs[w << 6]);
  gload16(srcK, &Ks[w << 6]);
  __syncthreads();

  for (int it = 0; it < 24; ++it) {
    int cur = (it & 1) << 9;
    if (it < 23) {
      int k0n = (it + 1) * 32;
      gload16(srcQ + k0n, &Qs[(cur ^ 512) + (w << 6)]);
      gload16(srcK + k0n, &Ks[(cur ^ 512) + (w << 6)]);
    }
    int kc = l >> 4;
    int ar = w * 16 + (l & 15);
    short8 a = Qs[cur + (ar << 2) + (kc ^ ((ar >> 1) & 3))];
    short8 bb[8];
#pragma unroll
    for (int j = 0; j < 8; ++j) {
      int br = j * 16 + (l & 15);
      bb[j] = Ks[cur + (br << 2) + (kc ^ ((br >> 1) & 3))];
    }
#pragma unroll
    for (int j = 0; j < 8; ++j)
      acc[j] = __builtin_amdgcn_mfma_f32_16x16x32_bf16(a, bb[j], acc[j], 0, 0, 0);
    __syncthreads();
  }

  const float scale = 0.03608439182435161f; // 1/sqrt(768)
  float colsum[8];
#pragma unroll
  for (int j = 0; j < 8; ++j) colsum[j] = 0.f;

#pragma unroll
  for (int r = 0; r < 4; ++r) {
    // row = w*16 + (l>>4)*4 + r ; cols j*16+(l&15)
    float mx = -3.0e38f;
#pragma unroll
    for (int j = 0; j < 8; ++j) mx = fmaxf(mx, acc[j][r]);
    mx = fmaxf(mx, __shfl_xor(mx, 1));
    mx = fmaxf(mx, __shfl_xor(mx, 2));
    mx = fmaxf(mx, __shfl_xor(mx, 4));
    mx = fmaxf(mx, __shfl_xor(mx, 8));
    float pv[8], sm = 0.f;
#pragma unroll
    for (int j = 0; j < 8; ++j) { pv[j] = __expf((acc[j][r] - mx) * scale); sm += pv[j]; }
    sm += __shfl_xor(sm, 1);
    sm += __shfl_xor(sm, 2);
    sm += __shfl_xor(sm, 4);
    sm += __shfl_xor(sm, 8);
    float inv = 1.f / sm;
#pragma unroll
    for (int j = 0; j < 8; ++j) colsum[j] += pv[j] * inv;
  }
#pragma unroll
  for (int j = 0; j < 8; ++j) {
    colsum[j] += __shfl_xor(colsum[j], 16);
    colsum[j] += __shfl_xor(colsum[j], 32);
  }
  if (l < 16) {
#pragma unroll
    for (int j = 0; j < 8; ++j) atomicAdd(&pb[j * 16 + l], colsum[j]);
  }
  __syncthreads();

  // PV: d = tid for all; d2 = (tid&255)+512 (valid contribution only for tid<256;
  // threads >=256 duplicate loads harmlessly to avoid divergence)
  int d2 = (tid & 255) + 512;
  float ctx0 = 0.f, ctx1 = 0.f;
  const short* vb = Vb + (size_t)b * 128 * D;
  for (int m = 0; m < 128; ++m) {
    float p = pb[m];
    const short* row = vb + (size_t)m * D;
    ctx0 += p * bf2f(row[tid]);
    ctx1 += p * bf2f(row[d2]);
  }
  ctx0 *= (1.f / 128.f);
  ctx1 *= (1.f / 128.f);
  bool lo = tid < 256;

  // LayerNorm over 768 values spread across 512 threads
  float mu = blockSum512(ctx0 + (lo ? ctx1 : 0.f), red, tid) * (1.f / 768.f);
  float c0 = ctx0 - mu, c1 = ctx1 - mu;
  float vs = c0 * c0 + (lo ? c1 * c1 : 0.f);
  float var = blockSum512(vs, red, tid) * (1.f / 768.f);
  float rstd = rsqrtf(var + 1e-5f);

  const short* em = MOEb + (size_t)(n * 129) * D;
  float cl0 = c0 * rstd * ln_w[tid] + ln_b[tid];
  float cl1 = c1 * rstd * ln_w[d2] + ln_b[d2];
  float g2l_p = bf2f(em[tid]) * cl0 + (lo ? bf2f(em[d2]) * cl1 : 0.f);
  float g2g_p = mcls[(size_t)b * D + tid] * ecls[(size_t)n * D + tid] +
                (lo ? mcls[(size_t)b * D + d2] * ecls[(size_t)n * D + d2] : 0.f);
  float g2l = blockSum512(g2l_p, red, tid);
  float g2g = blockSum512(g2g_p, red, tid);
  if (tid == 0) out[b * 32 + n] = 0.5f * (g2l + g2g);
}

extern "C" void kernel_launch(void* const* d_in, const int* in_sizes, int n_in,
                              void* d_out, int out_size, void* d_ws, size_t ws_size,
                              hipStream_t stream) {
  const float* ecls   = (const float*)d_in[0];
  const float* etok   = (const float*)d_in[1];
  const float* mcls   = (const float*)d_in[2];
  const float* mtok   = (const float*)d_in[3];
  const float* gate_w = (const float*)d_in[4];
  const float* gate_b = (const float*)d_in[5];
  const float* exp_w  = (const float*)d_in[6];
  const float* exp_b  = (const float*)d_in[7];
  const float* wq     = (const float*)d_in[8];
  const float* bq     = (const float*)d_in[9];
  const float* wk     = (const float*)d_in[10];
  const float* bk     = (const float*)d_in[11];
  const float* wv     = (const float*)d_in[12];
  const float* bv     = (const float*)d_in[13];
  const float* ln_w   = (const float*)d_in[14];
  const float* ln_b   = (const float*)d_in[15];
  float* outp = (float*)d_out;

  char* ws = (char*)d_ws;
  short* Qb    = (short*)(ws + 0);              //  6,291,456 B
  short* Kb    = (short*)(ws + 6291456);        //  3,145,728 B
  short* Vb    = (short*)(ws + 9437184);        //  3,145,728 B (ends 12,582,912)
  short* Xb    = (short*)(ws + 12582912);       //  9,510,912 B (ends 22,093,824)
  short* EO    = (short*)(ws + 22093824);       // 19,021,824 B (ends 41,115,648)
  short* MOEb  = (short*)(ws + 41115648);       //  9,510,912 B (ends 50,626,560)
  short* expwT = (short*)(ws + 50626560);       //  9,437,184 B (ends 60,063,744)
  short* wT    = (short*)(ws + 60063744);       //  3,538,944 B (ends 63,602,688)
  int*   te1   = (int*)  (ws + 63602688);       //     24,768 B each
  int*   te2   = (int*)  (ws + 63627456);
  float* tw1   = (float*)(ws + 63652224);
  float* tw2   = (float*)(ws + 63676992);
  int*   slot1 = (int*)  (ws + 63701760);
  int*   slot2 = (int*)  (ws + 63726528);
  int*   lst_tok = (int*)(ws + 63751296);       //     49,536 B
  int*   cnt   = (int*)  (ws + 63800832);       //         32 B
  int*   basee = (int*)  (ws + 63800864);       //         32 B  (total ~63.8 MB)

  prep_kernel<<<1548 + 1584, 256, 0, stream>>>(ecls, etok, mcls, mtok, gate_w, gate_b,
                                               exp_w, wq, wk, wv,
                                               te1, te2, tw1, tw2, Xb, expwT, wT);
  route_kernel<<<1, 1024, 0, stream>>>(te1, te2, lst_tok, slot1, slot2, cnt, basee);
  moe_kernel<<<49 * 6 * 8, 512, 0, stream>>>(Xb, expwT, cnt, basee, lst_tok, EO);
  combine_kernel<<<2322, 256, 0, stream>>>(EO, te1, te2, tw1, tw2, slot1, slot2,
                                           exp_b, MOEb);
  qkv_kernel<<<768, 512, 0, stream>>>(MOEb, wT, bq, bk, bv, Qb, Kb, Vb);
  attn_kernel<<<512, 512, 0, stream>>>(Qb, Kb, Vb, MOEb, ecls, mcls, ln_w, ln_b, outp);
}

// Round 11
// 121.253 us; speedup vs baseline: 1.3155x; 1.0302x over previous
//
#include <hip/hip_runtime.h>
#include <math.h>

#define D 768
#define NE 8
#define NTOK 6192      // 32*129 + 16*129
#define MEN_TOK0 4128  // 32*129

typedef __attribute__((ext_vector_type(8))) short short8;   // 8 x bf16
typedef __attribute__((ext_vector_type(4))) short short4b;  // 4 x bf16
typedef __attribute__((ext_vector_type(4))) float floatx4;  // MFMA C/D

__device__ __forceinline__ short f2bf(float f) {
  union { float f; unsigned u; } x; x.f = f;
  unsigned r = x.u + 0x7fffu + ((x.u >> 16) & 1u);
  return (short)(r >> 16);
}
__device__ __forceinline__ float bf2f(short s) {
  union { unsigned u; float f; } x; x.u = ((unsigned)(unsigned short)s) << 16;
  return x.f;
}

// async global->LDS 16B: wave-uniform LDS base, per-lane global src
__device__ __forceinline__ void gload16(const short* g, short8* lds_base) {
  __builtin_amdgcn_global_load_lds(
      (const __attribute__((address_space(1))) unsigned int*)g,
      (__attribute__((address_space(3))) unsigned int*)lds_base,
      16, 0, 0);
}

// counted-vmcnt pipeline barrier: wait own loads (leave N newest in flight),
// THEN join waves (m201 template ordering: wait -> barrier)
#define PIPE_BAR(NSTR)                                            \
  do {                                                            \
    asm volatile("s_waitcnt vmcnt(" NSTR ")" ::: "memory");       \
    __builtin_amdgcn_sched_barrier(0);                            \
    __builtin_amdgcn_s_barrier();                                 \
    __builtin_amdgcn_sched_barrier(0);                            \
  } while (0)

// Map concatenated token index -> source row pointer (virtual concat, no copy).
__device__ __forceinline__ const float* token_row(int t,
    const float* __restrict__ ecls, const float* __restrict__ etok,
    const float* __restrict__ mcls, const float* __restrict__ mtok) {
  if (t < MEN_TOK0) {
    int n = t / 129, s = t - n * 129;
    return (s == 0) ? (ecls + n * D) : (etok + (size_t)(n * 128 + s - 1) * D);
  } else {
    int tm = t - MEN_TOK0;
    int b = tm / 129, s = tm - b * 129;
    return (s == 0) ? (mcls + b * D) : (mtok + (size_t)(b * 128 + s - 1) * D);
  }
}

// ---------------- prep: fused gate (blocks 0..1547) + weight transpose/cvt
__global__ __launch_bounds__(256) void prep_kernel(
    const float* __restrict__ ecls, const float* __restrict__ etok,
    const float* __restrict__ mcls, const float* __restrict__ mtok,
    const float* __restrict__ gate_w, const float* __restrict__ gate_b,
    const float* __restrict__ exp_w, const float* __restrict__ wq,
    const float* __restrict__ wk, const float* __restrict__ wv,
    int* __restrict__ te1, int* __restrict__ te2,
    float* __restrict__ tw1, float* __restrict__ tw2,
    short* __restrict__ Xb, short* __restrict__ expwT, short* __restrict__ wT) {
  __shared__ float tbuf[64][65];
  int bid = blockIdx.x;
  int tid = threadIdx.x;
  if (bid < 1548) {
    int t = bid * 4 + (tid >> 6);
    int lane = tid & 63;
    const float* xr = token_row(t, ecls, etok, mcls, mtok);
    float acc[NE];
#pragma unroll
    for (int e = 0; e < NE; ++e) acc[e] = 0.f;
#pragma unroll
    for (int it = 0; it < 3; ++it) {
      int d0 = lane * 4 + it * 256;
      floatx4 x = *(const floatx4*)(xr + d0);
      short4b xb;
#pragma unroll
      for (int q = 0; q < 4; ++q) {
        xb[q] = f2bf(x[q]);
        float xv = x[q];
#pragma unroll
        for (int e = 0; e < NE; ++e) acc[e] += xv * gate_w[(d0 + q) * NE + e];
      }
      *(short4b*)(Xb + (size_t)t * D + d0) = xb;
    }
#pragma unroll
    for (int e = 0; e < NE; ++e) {
#pragma unroll
      for (int off = 32; off > 0; off >>= 1) acc[e] += __shfl_down(acc[e], off);
    }
    if (lane == 0) {
      float lg[NE];
#pragma unroll
      for (int e = 0; e < NE; ++e) lg[e] = acc[e] + gate_b[e];
      int e1 = 0;
#pragma unroll
      for (int e = 1; e < NE; ++e) if (lg[e] > lg[e1]) e1 = e;
      int e2 = (e1 == 0) ? 1 : 0;
#pragma unroll
      for (int e = 0; e < NE; ++e) {
        if (e != e1 && lg[e] > lg[e2]) e2 = e;
      }
      float w1 = 1.f / (1.f + __expf(lg[e2] - lg[e1]));
      te1[t] = e1; te2[t] = e2;
      tw1[t] = w1; tw2[t] = 1.f - w1;
    }
  } else {
    int zz = bid - 1548;
    int z = zz / 144, rem = zz % 144;
    int k0 = (rem / 12) * 64, o0 = (rem % 12) * 64;
    const float* src; short* dst;
    if (z < 8) { src = exp_w + (size_t)z * D * D; dst = expwT + (size_t)z * D * D; }
    else { src = (z == 8) ? wq : (z == 9) ? wk : wv; dst = wT + (size_t)(z - 8) * D * D; }
    int tx = tid & 63, ty = tid >> 6;
#pragma unroll
    for (int i = 0; i < 16; ++i) {
      int k = i * 4 + ty;
      tbuf[k][tx] = src[(size_t)(k0 + k) * D + o0 + tx];
    }
    __syncthreads();
#pragma unroll
    for (int i = 0; i < 16; ++i) {
      int o = i * 4 + ty;
      dst[(size_t)(o0 + o) * D + k0 + tx] = f2bf(tbuf[tx][o]);
    }
  }
}

// ---------------- route: fused histogram + compaction (single block, LDS atomics)
__global__ __launch_bounds__(1024) void route_kernel(
    const int* __restrict__ te1, const int* __restrict__ te2,
    int* __restrict__ lst_tok, int* __restrict__ slot1, int* __restrict__ slot2,
    int* __restrict__ cnt, int* __restrict__ basee) {
  __shared__ int hist[NE];
  __shared__ int base_s[NE];
  int tid = threadIdx.x;
  if (tid < NE) hist[tid] = 0;
  __syncthreads();
  for (int t = tid; t < NTOK; t += 1024) {
    atomicAdd(&hist[te1[t]], 1);
    atomicAdd(&hist[te2[t]], 1);
  }
  __syncthreads();
  if (tid == 0) {
    int acc = 0;
    for (int e = 0; e < NE; ++e) {
      base_s[e] = acc;
      cnt[e] = hist[e];
      basee[e] = acc;
      acc += hist[e];
    }
  }
  __syncthreads();
  if (tid < NE) hist[tid] = 0;
  __syncthreads();
  for (int t = tid; t < NTOK; t += 1024) {
    int e1 = te1[t], e2 = te2[t];
    int r1 = atomicAdd(&hist[e1], 1);
    int r2 = atomicAdd(&hist[e2], 1);
    int s1 = base_s[e1] + r1;
    int s2 = base_s[e2] + r2;
    slot1[t] = s1; slot2[t] = s2;
    lst_tok[s1] = t; lst_tok[s2] = t;
  }
}

// ---------------- grouped expert GEMM (MFMA bf16), 128x128, BK=32, 3-buf pipeline
// 512 threads / 8 waves (4 row-groups x 2 col-groups of 32x64)
__global__ __launch_bounds__(512, 4) void moe_kernel(
    const short* __restrict__ Xb, const short* __restrict__ expwT,
    const int* __restrict__ cnt, const int* __restrict__ basee,
    const int* __restrict__ lst_tok, short* __restrict__ EO) {
  int id = blockIdx.x;
  int e = id & 7;
  int r = id >> 3;
  int ob = r % 6;
  int tb = r / 6;
  int count = cnt[e];
  int t0 = tb * 128;
  if (t0 >= count) return;
  int o0 = ob * 128;
  int gb = basee[e];

  __shared__ short8 As[1536];   // 3 bufs x 512 slots (128 rows x 4 chunks)
  __shared__ short8 Bs[1536];
  __shared__ int stok[128];

  int tid = threadIdx.x;
  int l = tid & 63, w = tid >> 6;   // w 0..7
  int wr = w >> 1, wc = w & 1;

  if (tid < 128) {
    int p = t0 + tid;
    stok[tid] = lst_tok[gb + (p < count ? p : 0)];
  }
  __syncthreads();   // full sync: stok visible, vmcnt drained

  const short* Bg = expwT + (size_t)e * D * D;
  int srow = tid >> 2, scc = tid & 3;
  int csrc = (scc ^ ((srow >> 1) & 3)) * 8;
  const short* srcA = Xb + (size_t)stok[srow] * D + csrc;
  const short* srcB = Bg + (size_t)(o0 + srow) * D + csrc;

  floatx4 acc[2][4];
#pragma unroll
  for (int ai = 0; ai < 2; ++ai)
#pragma unroll
    for (int bj = 0; bj < 4; ++bj) acc[ai][bj] = (floatx4){0.f, 0.f, 0.f, 0.f};

  // prologue: stage tiles 0,1 (order A0,B0,A1,B1 -> vmcnt(2) leaves A1,B1)
  gload16(srcA, &As[w << 6]);
  gload16(srcB, &Bs[w << 6]);
  gload16(srcA + 32, &As[512 + (w << 6)]);
  gload16(srcB + 32, &Bs[512 + (w << 6)]);

  for (int it = 0; it < 24; ++it) {
    if (it < 23) PIPE_BAR("2"); else PIPE_BAR("0");
    int cur = (it % 3) << 9;
    if (it < 22) {
      int nb = ((it + 2) % 3) << 9;
      int k0n = (it + 2) * 32;
      gload16(srcA + k0n, &As[nb + (w << 6)]);
      gload16(srcB + k0n, &Bs[nb + (w << 6)]);
    }
    int kc = l >> 4;
    short8 a[2], bb[4];
#pragma unroll
    for (int ai = 0; ai < 2; ++ai) {
      int ar = wr * 32 + ai * 16 + (l & 15);
      a[ai] = As[cur + (ar << 2) + (kc ^ ((ar >> 1) & 3))];
    }
#pragma unroll
    for (int bj = 0; bj < 4; ++bj) {
      int br = wc * 64 + bj * 16 + (l & 15);
      bb[bj] = Bs[cur + (br << 2) + (kc ^ ((br >> 1) & 3))];
    }
#pragma unroll
    for (int ai = 0; ai < 2; ++ai)
#pragma unroll
      for (int bj = 0; bj < 4; ++bj)
        acc[ai][bj] = __builtin_amdgcn_mfma_f32_16x16x32_bf16(a[ai], bb[bj], acc[ai][bj], 0, 0, 0);
  }

  // epilogue: C/D layout col=lane&15, row=(lane>>4)*4+reg
#pragma unroll
  for (int ai = 0; ai < 2; ++ai) {
#pragma unroll
    for (int rr = 0; rr < 4; ++rr) {
      int rowl = wr * 32 + ai * 16 + ((l >> 4) << 2) + rr;
      int p = t0 + rowl;
      if (p < count) {
        size_t off = (size_t)(gb + p) * D;
#pragma unroll
        for (int bj = 0; bj < 4; ++bj) {
          int col = o0 + wc * 64 + bj * 16 + (l & 15);
          EO[off + col] = f2bf(acc[ai][bj][rr]);
        }
      }
    }
  }
}

// ---------------- combine: MOEb[t] = w1*(EO[s1]+b_e1) + w2*(EO[s2]+b_e2)
__global__ __launch_bounds__(256) void combine_kernel(
    const short* __restrict__ EO,
    const int* __restrict__ te1, const int* __restrict__ te2,
    const float* __restrict__ tw1, const float* __restrict__ tw2,
    const int* __restrict__ slot1, const int* __restrict__ slot2,
    const float* __restrict__ exp_b, short* __restrict__ MOEb) {
  int idx = blockIdx.x * 256 + threadIdx.x;   // 6192*96 total
  int t = idx / 96, cg = idx - t * 96;
  int c0 = cg * 8;
  int e1 = te1[t], e2 = te2[t];
  float w1 = tw1[t], w2 = tw2[t];
  short8 a = *(const short8*)(EO + (size_t)slot1[t] * D + c0);
  short8 b = *(const short8*)(EO + (size_t)slot2[t] * D + c0);
  const float* b1 = exp_b + e1 * D + c0;
  const float* b2 = exp_b + e2 * D + c0;
  short8 o;
#pragma unroll
  for (int j = 0; j < 8; ++j)
    o[j] = f2bf(w1 * (bf2f(a[j]) + b1[j]) + w2 * (bf2f(b[j]) + b2[j]));
  *(short8*)(MOEb + (size_t)t * D + c0) = o;
}

// ---------------- QKV projections (MFMA bf16), 64x128, BK=32, 3-buf pipeline
// 512 threads / 8 waves (4 row-groups x 2 col-groups of 16x64)
__global__ __launch_bounds__(512, 4) void qkv_kernel(
    const short* __restrict__ MOEb, const short* __restrict__ wT,
    const float* __restrict__ bq, const float* __restrict__ bk,
    const float* __restrict__ bv,
    short* __restrict__ Qb, short* __restrict__ Kb, short* __restrict__ Vb) {
  int id = blockIdx.x;
  int z, r;
  if (id < 384)      { z = 0; r = id; }
  else if (id < 576) { z = 1; r = id - 384; }
  else               { z = 2; r = id - 576; }
  int tb = r / 6, ob = r % 6;
  int o0 = ob * 128;
  int base = (z == 0) ? 0 : MEN_TOK0;
  const short* W = wT + (size_t)z * D * D;
  const float* bias = (z == 0) ? bq : (z == 1) ? bk : bv;
  int tokbase = base + (tb >> 1) * 129 + 1 + (tb & 1) * 64;
  const short* Ag = MOEb + (size_t)tokbase * D;

  __shared__ short8 As[768];    // 3 bufs x 256 slots (64 rows x 4 chunks)
  __shared__ short8 Bs[1536];   // 3 bufs x 512 slots

  int tid = threadIdx.x;
  int l = tid & 63, w = tid >> 6;   // w 0..7
  int wr = w >> 1, wc = w & 1;

  int srow = tid >> 2, scc = tid & 3;
  int csrc = (scc ^ ((srow >> 1) & 3)) * 8;
  const short* srcA = Ag + (size_t)(srow & 63) * D + csrc;   // used only by w<4
  const short* srcB = W + (size_t)(o0 + srow) * D + csrc;

  floatx4 acc[4];
#pragma unroll
  for (int bj = 0; bj < 4; ++bj) acc[bj] = (floatx4){0.f, 0.f, 0.f, 0.f};

  // prologue (w<4: A0,B0,A1,B1 -> wait 2; w>=4: B0,B1 -> wait 1)
  if (w < 4) gload16(srcA, &As[w << 6]);
  gload16(srcB, &Bs[w << 6]);
  if (w < 4) gload16(srcA + 32, &As[256 + (w << 6)]);
  gload16(srcB + 32, &Bs[512 + (w << 6)]);

  for (int it = 0; it < 24; ++it) {
    if (it < 23) {
      if (w < 4) {
        asm volatile("s_waitcnt vmcnt(2)" ::: "memory");
      } else {
        asm volatile("s_waitcnt vmcnt(1)" ::: "memory");
      }
    } else {
      asm volatile("s_waitcnt vmcnt(0)" ::: "memory");
    }
    __builtin_amdgcn_sched_barrier(0);
    __builtin_amdgcn_s_barrier();
    __builtin_amdgcn_sched_barrier(0);

    int curA = (it % 3) << 8;
    int curB = (it % 3) << 9;
    if (it < 22) {
      int nb = (it + 2) % 3;
      int k0n = (it + 2) * 32;
      if (w < 4) gload16(srcA + k0n, &As[(nb << 8) + (w << 6)]);
      gload16(srcB + k0n, &Bs[(nb << 9) + (w << 6)]);
    }
    int kc = l >> 4;
    int ar = wr * 16 + (l & 15);
    short8 a = As[curA + (ar << 2) + (kc ^ ((ar >> 1) & 3))];
    short8 bb[4];
#pragma unroll
    for (int bj = 0; bj < 4; ++bj) {
      int br = wc * 64 + bj * 16 + (l & 15);
      bb[bj] = Bs[curB + (br << 2) + (kc ^ ((br >> 1) & 3))];
    }
#pragma unroll
    for (int bj = 0; bj < 4; ++bj)
      acc[bj] = __builtin_amdgcn_mfma_f32_16x16x32_bf16(a, bb[bj], acc[bj], 0, 0, 0);
  }

#pragma unroll
  for (int rr = 0; rr < 4; ++rr) {
    int rowl = wr * 16 + ((l >> 4) << 2) + rr;
    size_t rglob = (size_t)tb * 64 + rowl;
#pragma unroll
    for (int bj = 0; bj < 4; ++bj) {
      int col = o0 + wc * 64 + bj * 16 + (l & 15);
      float v = acc[bj][rr] + bias[col];
      if (z == 0)      Qb[rglob * D + col] = f2bf(v);
      else if (z == 1) Kb[rglob * D + col] = f2bf(v);
      else             Vb[rglob * D + col] = f2bf(v);
    }
  }
}

__device__ __forceinline__ float blockSum512(float v, volatile float* red, int tid) {
#pragma unroll
  for (int off = 32; off > 0; off >>= 1) v += __shfl_down(v, off);
  __syncthreads();
  if ((tid & 63) == 0) red[tid >> 6] = v;
  __syncthreads();
  float s = 0.f;
#pragma unroll
  for (int i = 0; i < 8; ++i) s += red[i];
  return s;
}

// ---------------- FUSED attention: scores GEMM + softmax + colmean + PV + LN + dots
// 512 threads / 8 waves, 3-buf counted-vmcnt pipeline. one block per (b,n)
__global__ __launch_bounds__(512, 4) void attn_kernel(
    const short* __restrict__ Qb, const short* __restrict__ Kb,
    const short* __restrict__ Vb, const short* __restrict__ MOEb,
    const float* __restrict__ ecls, const float* __restrict__ mcls,
    const float* __restrict__ ln_w, const float* __restrict__ ln_b,
    float* __restrict__ out) {
  int id = blockIdx.x;
  int n = id & 31, b = id >> 5;
  __shared__ short8 Qs[1536];   // 3 bufs x 512 slots (128 rows x 4 chunks)
  __shared__ short8 Ks[1536];
  __shared__ float pb[128];
  __shared__ float red[8];
  int tid = threadIdx.x;
  int l = tid & 63, w = tid >> 6;   // w 0..7
  if (tid < 128) pb[tid] = 0.f;
  __syncthreads();   // pb visible; clean vmcnt slate before pipeline

  floatx4 acc[8];
#pragma unroll
  for (int j = 0; j < 8; ++j) acc[j] = (floatx4){0.f, 0.f, 0.f, 0.f};

  const short* qg = Qb + (size_t)n * 128 * D;
  const short* kg = Kb + (size_t)b * 128 * D;

  int srow = tid >> 2, scc = tid & 3;
  int csrc = (scc ^ ((srow >> 1) & 3)) * 8;
  const short* srcQ = qg + (size_t)srow * D + csrc;
  const short* srcK = kg + (size_t)srow * D + csrc;

  // prologue: Q0,K0,Q1,K1 -> vmcnt(2) leaves Q1,K1
  gload16(srcQ, &Qs[w << 6]);
  gload16(srcK, &Ks[w << 6]);
  gload16(srcQ + 32, &Qs[512 + (w << 6)]);
  gload16(srcK + 32, &Ks[512 + (w << 6)]);

  for (int it = 0; it < 24; ++it) {
    if (it < 23) PIPE_BAR("2"); else PIPE_BAR("0");
    int cur = (it % 3) << 9;
    if (it < 22) {
      int nb = ((it + 2) % 3) << 9;
      int k0n = (it + 2) * 32;
      gload16(srcQ + k0n, &Qs[nb + (w << 6)]);
      gload16(srcK + k0n, &Ks[nb + (w << 6)]);
    }
    int kc = l >> 4;
    int ar = w * 16 + (l & 15);
    short8 a = Qs[cur + (ar << 2) + (kc ^ ((ar >> 1) & 3))];
    short8 bb[8];
#pragma unroll
    for (int j = 0; j < 8; ++j) {
      int br = j * 16 + (l & 15);
      bb[j] = Ks[cur + (br << 2) + (kc ^ ((br >> 1) & 3))];
    }
#pragma unroll
    for (int j = 0; j < 8; ++j)
      acc[j] = __builtin_amdgcn_mfma_f32_16x16x32_bf16(a, bb[j], acc[j], 0, 0, 0);
  }

  const float scale = 0.03608439182435161f; // 1/sqrt(768)
  float colsum[8];
#pragma unroll
  for (int j = 0; j < 8; ++j) colsum[j] = 0.f;

#pragma unroll
  for (int r = 0; r < 4; ++r) {
    // row = w*16 + (l>>4)*4 + r ; cols j*16+(l&15)
    float mx = -3.0e38f;
#pragma unroll
    for (int j = 0; j < 8; ++j) mx = fmaxf(mx, acc[j][r]);
    mx = fmaxf(mx, __shfl_xor(mx, 1));
    mx = fmaxf(mx, __shfl_xor(mx, 2));
    mx = fmaxf(mx, __shfl_xor(mx, 4));
    mx = fmaxf(mx, __shfl_xor(mx, 8));
    float pv[8], sm = 0.f;
#pragma unroll
    for (int j = 0; j < 8; ++j) { pv[j] = __expf((acc[j][r] - mx) * scale); sm += pv[j]; }
    sm += __shfl_xor(sm, 1);
    sm += __shfl_xor(sm, 2);
    sm += __shfl_xor(sm, 4);
    sm += __shfl_xor(sm, 8);
    float inv = 1.f / sm;
#pragma unroll
    for (int j = 0; j < 8; ++j) colsum[j] += pv[j] * inv;
  }
#pragma unroll
  for (int j = 0; j < 8; ++j) {
    colsum[j] += __shfl_xor(colsum[j], 16);
    colsum[j] += __shfl_xor(colsum[j], 32);
  }
  if (l < 16) {
#pragma unroll
    for (int j = 0; j < 8; ++j) atomicAdd(&pb[j * 16 + l], colsum[j]);
  }
  __syncthreads();   // full sync: pb atomics visible

  // PV: thread t<192 handles dims 4t..4t+3 (short4b loads; 768 = 192*4)
  float ctx[4] = {0.f, 0.f, 0.f, 0.f};
  bool act = tid < 192;
  int d0 = tid << 2;
  if (act) {
    const short* vb = Vb + (size_t)b * 128 * D + d0;
    for (int m = 0; m < 128; ++m) {
      float p = pb[m];
      short4b v = *(const short4b*)(vb + (size_t)m * D);
#pragma unroll
      for (int j = 0; j < 4; ++j) ctx[j] += p * bf2f(v[j]);
    }
#pragma unroll
    for (int j = 0; j < 4; ++j) ctx[j] *= (1.f / 128.f);
  }

  // LayerNorm over 768 values held by threads 0..191
  float mu = blockSum512(ctx[0] + ctx[1] + ctx[2] + ctx[3], red, tid) * (1.f / 768.f);
  float c[4];
#pragma unroll
  for (int j = 0; j < 4; ++j) c[j] = ctx[j] - mu;
  float vs = act ? (c[0]*c[0] + c[1]*c[1] + c[2]*c[2] + c[3]*c[3]) : 0.f;
  float var = blockSum512(vs, red, tid) * (1.f / 768.f);
  float rstd = rsqrtf(var + 1e-5f);

  float g2l_p = 0.f, g2g_p = 0.f;
  if (act) {
    floatx4 lw = *(const floatx4*)(ln_w + d0);
    floatx4 lb = *(const floatx4*)(ln_b + d0);
    short4b em = *(const short4b*)(MOEb + (size_t)(n * 129) * D + d0);
    floatx4 mc = *(const floatx4*)(mcls + (size_t)b * D + d0);
    floatx4 ec = *(const floatx4*)(ecls + (size_t)n * D + d0);
#pragma unroll
    for (int j = 0; j < 4; ++j) {
      float cl = c[j] * rstd * lw[j] + lb[j];
      g2l_p += bf2f(em[j]) * cl;
      g2g_p += mc[j] * ec[j];
    }
  }
  float g2l = blockSum512(g2l_p, red, tid);
  float g2g = blockSum512(g2g_p, red, tid);
  if (tid == 0) out[b * 32 + n] = 0.5f * (g2l + g2g);
}

extern "C" void kernel_launch(void* const* d_in, const int* in_sizes, int n_in,
                              void* d_out, int out_size, void* d_ws, size_t ws_size,
                              hipStream_t stream) {
  const float* ecls   = (const float*)d_in[0];
  const float* etok   = (const float*)d_in[1];
  const float* mcls   = (const float*)d_in[2];
  const float* mtok   = (const float*)d_in[3];
  const float* gate_w = (const float*)d_in[4];
  const float* gate_b = (const float*)d_in[5];
  const float* exp_w  = (const float*)d_in[6];
  const float* exp_b  = (const float*)d_in[7];
  const float* wq     = (const float*)d_in[8];
  const float* bq     = (const float*)d_in[9];
  const float* wk     = (const float*)d_in[10];
  const float* bk     = (const float*)d_in[11];
  const float* wv     = (const float*)d_in[12];
  const float* bv     = (const float*)d_in[13];
  const float* ln_w   = (const float*)d_in[14];
  const float* ln_b   = (const float*)d_in[15];
  float* outp = (float*)d_out;

  char* ws = (char*)d_ws;
  short* Qb    = (short*)(ws + 0);              //  6,291,456 B
  short* Kb    = (short*)(ws + 6291456);        //  3,145,728 B
  short* Vb    = (short*)(ws + 9437184);        //  3,145,728 B (ends 12,582,912)
  short* Xb    = (short*)(ws + 12582912);       //  9,510,912 B (ends 22,093,824)
  short* EO    = (short*)(ws + 22093824);       // 19,021,824 B (ends 41,115,648)
  short* MOEb  = (short*)(ws + 41115648);       //  9,510,912 B (ends 50,626,560)
  short* expwT = (short*)(ws + 50626560);       //  9,437,184 B (ends 60,063,744)
  short* wT    = (short*)(ws + 60063744);       //  3,538,944 B (ends 63,602,688)
  int*   te1   = (int*)  (ws + 63602688);       //     24,768 B each
  int*   te2   = (int*)  (ws + 63627456);
  float* tw1   = (float*)(ws + 63652224);
  float* tw2   = (float*)(ws + 63676992);
  int*   slot1 = (int*)  (ws + 63701760);
  int*   slot2 = (int*)  (ws + 63726528);
  int*   lst_tok = (int*)(ws + 63751296);       //     49,536 B
  int*   cnt   = (int*)  (ws + 63800832);       //         32 B
  int*   basee = (int*)  (ws + 63800864);       //         32 B  (total ~63.8 MB)

  prep_kernel<<<1548 + 1584, 256, 0, stream>>>(ecls, etok, mcls, mtok, gate_w, gate_b,
                                               exp_w, wq, wk, wv,
                                               te1, te2, tw1, tw2, Xb, expwT, wT);
  route_kernel<<<1, 1024, 0, stream>>>(te1, te2, lst_tok, slot1, slot2, cnt, basee);
  moe_kernel<<<49 * 6 * 8, 512, 0, stream>>>(Xb, expwT, cnt, basee, lst_tok, EO);
  combine_kernel<<<2322, 256, 0, stream>>>(EO, te1, te2, tw1, tw2, slot1, slot2,
                                           exp_b, MOEb);
  qkv_kernel<<<768, 512, 0, stream>>>(MOEb, wT, bq, bk, bv, Qb, Kb, Vb);
  attn_kernel<<<512, 512, 0, stream>>>(Qb, Kb, Vb, MOEb, ecls, mcls, ln_w, ln_b, outp);
}